// Round 6
// baseline (248.059 us; speedup 1.0000x reference)
//
#include <hip/hip_runtime.h>

#define NN   50000
#define NE   600000
#define HID  128
#define NOUT_ 64
#define NG   256

#define SCAN_CHUNK 1024
#define SCAN_NB ((NN + SCAN_CHUNK - 1) / SCAN_CHUNK)  // 49

typedef unsigned int u32;
typedef unsigned short u16;
typedef __attribute__((ext_vector_type(8))) short s16x8;  // 8 bf16 (4 VGPRs)
typedef __attribute__((ext_vector_type(4))) float f32x4;

// bf16 helpers (bit ops; accumulate in f32, store RNE bf16)
static __device__ __forceinline__ float bflo(u32 u) { return __uint_as_float(u << 16); }
static __device__ __forceinline__ float bfhi(u32 u) { return __uint_as_float(u & 0xffff0000u); }
static __device__ __forceinline__ u32 pack2bf(float lo, float hi) {
  u32 ul = __float_as_uint(lo), uh = __float_as_uint(hi);
  ul = (ul + 0x7fffu + ((ul >> 16) & 1u)) >> 16;
  uh = (uh + 0x7fffu + ((uh >> 16) & 1u)) >> 16;
  return ul | (uh << 16);
}
static __device__ __forceinline__ u16 bf16rne(float f) {
  u32 u = __float_as_uint(f);
  u = (u + 0x7fffu + ((u >> 16) & 1u)) >> 16;
  return (u16)u;
}

// ---- init / CSR build ------------------------------------------------------

static __global__ void k_zero(int* __restrict__ cnts, int* __restrict__ cursor) {
  int i = (blockIdx.x * 256 + threadIdx.x) * 4;
  if (i < NN) {  // NN % 4 == 0
    *reinterpret_cast<int4*>(&cnts[i]) = make_int4(0, 0, 0, 0);
    *reinterpret_cast<int4*>(&cursor[i]) = make_int4(0, 0, 0, 0);
  }
}

static __global__ void k_count(const int* __restrict__ row, int* __restrict__ cnts) {
  int e = blockIdx.x * 256 + threadIdx.x;
  if (e < NE) atomicAdd(&cnts[row[e]], 1);
}

static __global__ __launch_bounds__(256) void k_scan1(const int* __restrict__ cnts,
                                                      int* __restrict__ bsum) {
  __shared__ int red[4];
  const int b = blockIdx.x, tid = threadIdx.x;
  const int start = b * SCAN_CHUNK + tid * 4;
  int s = 0;
#pragma unroll
  for (int i = 0; i < 4; ++i) {
    int idx = start + i;
    if (idx < NN) s += cnts[idx];
  }
#pragma unroll
  for (int o = 1; o < 64; o <<= 1) s += __shfl_xor(s, o);
  if ((tid & 63) == 0) red[tid >> 6] = s;
  __syncthreads();
  if (tid == 0) bsum[b] = red[0] + red[1] + red[2] + red[3];
}

static __global__ void k_scan2(const int* __restrict__ bsum, int* __restrict__ boff) {
  const int tid = threadIdx.x;  // 64 threads
  int orig = (tid < SCAN_NB) ? bsum[tid] : 0;
  int v = orig;
#pragma unroll
  for (int o = 1; o < 64; o <<= 1) {
    int u = __shfl_up(v, o);
    if (tid >= o) v += u;
  }
  if (tid < SCAN_NB) boff[tid] = v - orig;
}

static __global__ __launch_bounds__(256) void k_scan3(const int* __restrict__ cnts,
                                                      const int* __restrict__ boff,
                                                      int* __restrict__ base,
                                                      float* __restrict__ dinv) {
  __shared__ int wsum[4];
  const int b = blockIdx.x, tid = threadIdx.x;
  const int start = b * SCAN_CHUNK + tid * 4;
  int c[4];
  int s = 0;
#pragma unroll
  for (int i = 0; i < 4; ++i) {
    int idx = start + i;
    c[i] = (idx < NN) ? cnts[idx] : 0;
    s += c[i];
  }
  const int orig = s;
  const int lane = tid & 63, w = tid >> 6;
#pragma unroll
  for (int o = 1; o < 64; o <<= 1) {
    int u = __shfl_up(s, o);
    if (lane >= o) s += u;
  }
  if (lane == 63) wsum[w] = s;
  __syncthreads();
  int ex = s - orig + boff[b];
  for (int i = 0; i < w; ++i) ex += wsum[i];
#pragma unroll
  for (int i = 0; i < 4; ++i) {
    int idx = start + i;
    if (idx < NN) {
      base[idx] = ex;
      ex += c[i];
      dinv[idx] = rsqrtf((float)(c[i] + 1));  // +1 self-loop
    }
  }
  if (b == 0 && tid == 0) base[NN] = NE;
}

static __global__ void k_scatter(const int* __restrict__ row, const int* __restrict__ col,
                                 const int* __restrict__ base, int* __restrict__ cursor,
                                 int* __restrict__ colIdx) {
  int e = blockIdx.x * 256 + threadIdx.x;
  if (e >= NE) return;
  int r = row[e];
  int pos = base[r] + atomicAdd(&cursor[r], 1);
  colIdx[pos] = col[e];
}

// ---- weight split: W -> Whi + Wlo (bf16 each), error ~2^-17 ----------------

static __global__ void k_wsplit(const float* __restrict__ W1, const float* __restrict__ W2,
                                u16* __restrict__ whi, u16* __restrict__ wlo) {
  int i = blockIdx.x * 256 + threadIdx.x;  // 0..32767
  if (i >= 2 * HID * HID) return;
  float w = (i < HID * HID) ? W1[i] : W2[i - HID * HID];
  u16 hi = bf16rne(w);
  float fhi = __uint_as_float(((u32)hi) << 16);
  whi[i] = hi;
  wlo[i] = bf16rne(w - fhi);
}

// ---- MFMA GEMM: g(bf16) = (src @ W^T + b) * dinv[row] ----------------------
// A row = lane&15, k = (lane>>4)*8+j ; B col = lane&15, same k ;
// D col = lane&15, row = (lane>>4)*4+reg  (m89-verified layouts)

template <bool FIRST>
static __global__ __launch_bounds__(256) void k_gemm(
    const u16* __restrict__ x, const int* __restrict__ H,
    const float* __restrict__ emb,
    const u16* __restrict__ whi, const u16* __restrict__ wlo,
    const float* __restrict__ bias, const float* __restrict__ dinv,
    u16* __restrict__ g) {
  const int tid = threadIdx.x;
  const int wv = tid >> 6;        // wave 0..3
  const int l = tid & 63;
  const int l16 = l & 15, g4 = l >> 4;
  const int mrow = blockIdx.x * 64 + wv * 16 + l16;  // A-operand row for this lane
  const int msafe = mrow < NN ? mrow : NN - 1;

  f32x4 acc[8];
#pragma unroll
  for (int t = 0; t < 8; ++t) acc[t] = (f32x4){0.f, 0.f, 0.f, 0.f};

  int hidx = 0;
  if (FIRST) hidx = H[msafe];

#pragma unroll
  for (int s = 0; s < 4; ++s) {
    const int koff = s * 32 + g4 * 8;
    s16x8 a;
    if (FIRST) {
      const float* ep = &emb[(size_t)hidx * HID + koff];
      float4 u0 = *reinterpret_cast<const float4*>(ep);
      float4 u1 = *reinterpret_cast<const float4*>(ep + 4);
      union { s16x8 v; u32 w[4]; } au;
      au.w[0] = pack2bf(u0.x, u0.y);
      au.w[1] = pack2bf(u0.z, u0.w);
      au.w[2] = pack2bf(u1.x, u1.y);
      au.w[3] = pack2bf(u1.z, u1.w);
      a = au.v;
    } else {
      a = *reinterpret_cast<const s16x8*>(&x[(size_t)msafe * HID + koff]);
    }
#pragma unroll
    for (int t = 0; t < 8; ++t) {
      s16x8 bh = *reinterpret_cast<const s16x8*>(&whi[(size_t)(16 * t + l16) * HID + koff]);
      s16x8 bl = *reinterpret_cast<const s16x8*>(&wlo[(size_t)(16 * t + l16) * HID + koff]);
      acc[t] = __builtin_amdgcn_mfma_f32_16x16x32_bf16(a, bh, acc[t], 0, 0, 0);
      acc[t] = __builtin_amdgcn_mfma_f32_16x16x32_bf16(a, bl, acc[t], 0, 0, 0);
    }
  }

  // epilogue: D row = g4*4 + j, col = 16t + l16
  const int mbase = blockIdx.x * 64 + wv * 16 + g4 * 4;
  float dv[4];
#pragma unroll
  for (int j = 0; j < 4; ++j) {
    int m = mbase + j;
    dv[j] = dinv[m < NN ? m : NN - 1];
  }
#pragma unroll
  for (int t = 0; t < 8; ++t) {
    float bn = bias[16 * t + l16];
#pragma unroll
    for (int j = 0; j < 4; ++j) {
      int m = mbase + j;
      if (m < NN)
        g[(size_t)m * HID + 16 * t + l16] = bf16rne((acc[t][j] + bn) * dv[j]);
    }
  }
}

// x[node](bf16) = relu( dinv[node] * ( g[node] + sum_{c in adj(node)} g[c] ) )
static __global__ void k_csr(const int* __restrict__ base, const int* __restrict__ colIdx,
                             const u16* __restrict__ g, const float* __restrict__ dinv,
                             u16* __restrict__ x) {
  int t = blockIdx.x * 256 + threadIdx.x;
  int node = t >> 5;
  if (node >= NN) return;
  const int lane2 = (t & 31) * 2;  // u32 index within row (HID/2 = 64 u32)
  const u32* gw = (const u32*)g;

  uint2 v = *reinterpret_cast<const uint2*>(gw + (size_t)node * 64 + lane2);  // self
  float a0 = bflo(v.x), a1 = bfhi(v.x), a2 = bflo(v.y), a3 = bfhi(v.y);

  const int s = base[node], e = base[node + 1];
  int i = s;
  for (; i + 4 <= e; i += 4) {
    int c0 = colIdx[i], c1 = colIdx[i + 1], c2 = colIdx[i + 2], c3 = colIdx[i + 3];
    uint2 w0 = *reinterpret_cast<const uint2*>(gw + (size_t)c0 * 64 + lane2);
    uint2 w1 = *reinterpret_cast<const uint2*>(gw + (size_t)c1 * 64 + lane2);
    uint2 w2 = *reinterpret_cast<const uint2*>(gw + (size_t)c2 * 64 + lane2);
    uint2 w3 = *reinterpret_cast<const uint2*>(gw + (size_t)c3 * 64 + lane2);
    a0 += bflo(w0.x) + bflo(w1.x) + bflo(w2.x) + bflo(w3.x);
    a1 += bfhi(w0.x) + bfhi(w1.x) + bfhi(w2.x) + bfhi(w3.x);
    a2 += bflo(w0.y) + bflo(w1.y) + bflo(w2.y) + bflo(w3.y);
    a3 += bfhi(w0.y) + bfhi(w1.y) + bfhi(w2.y) + bfhi(w3.y);
  }
  for (; i < e; ++i) {
    uint2 w = *reinterpret_cast<const uint2*>(gw + (size_t)colIdx[i] * 64 + lane2);
    a0 += bflo(w.x); a1 += bfhi(w.x); a2 += bflo(w.y); a3 += bfhi(w.y);
  }
  float d = dinv[node];
  a0 = fmaxf(a0 * d, 0.f);
  a1 = fmaxf(a1 * d, 0.f);
  a2 = fmaxf(a2 * d, 0.f);
  a3 = fmaxf(a3 * d, 0.f);
  *reinterpret_cast<uint2*>((u32*)x + (size_t)node * 64 + lane2) =
      make_uint2(pack2bf(a0, a1), pack2bf(a2, a3));
}

// ---- fused mean-pool + head (batch is SORTED) ------------------------------

static __device__ __forceinline__ int lb(const int* __restrict__ b, int n, int v) {
  int lo = 0, hi = n;
  while (lo < hi) { int m = (lo + hi) >> 1; if (b[m] < v) lo = m + 1; else hi = m; }
  return lo;
}

static __global__ __launch_bounds__(256) void k_pool_out(
    const int* __restrict__ batch, const u16* __restrict__ x,
    const float* __restrict__ Wout, const float* __restrict__ bout,
    float* __restrict__ out) {
  const int g = blockIdx.x;
  const int tid = threadIdx.x;
  const int s = lb(batch, NN, g);
  const int e = lb(batch, NN, g + 1);
  const float inv = 1.0f / fmaxf((float)(e - s), 1.0f);

  const int d = tid & 127;
  const int half = tid >> 7;
  float acc = 0.f;
  for (int i = s + half; i < e; i += 2)
    acc += __uint_as_float(((u32)x[(size_t)i * HID + d]) << 16);

  __shared__ float tmp[256];
  __shared__ float pooled[HID];
  tmp[tid] = acc;
  __syncthreads();
  if (tid < HID) pooled[tid] = (tmp[tid] + tmp[tid + HID]) * inv;
  __syncthreads();

  const int o = tid >> 2, q = tid & 3;
  const float* wrow = &Wout[o * HID + q * 32];
  const float* prow = &pooled[q * 32];
  float a = 0.f;
#pragma unroll
  for (int k = 0; k < 32; k += 4) {
    float4 p = *reinterpret_cast<const float4*>(&prow[k]);
    float4 w = *reinterpret_cast<const float4*>(&wrow[k]);
    a += p.x * w.x + p.y * w.y + p.z * w.z + p.w * w.w;
  }
  a += __shfl_xor(a, 1);
  a += __shfl_xor(a, 2);
  if (q == 0) out[g * NOUT_ + o] = a + bout[o];
}

extern "C" void kernel_launch(void* const* d_in, const int* in_sizes, int n_in,
                              void* d_out, int out_size, void* d_ws, size_t ws_size,
                              hipStream_t stream) {
  const int* H     = (const int*)d_in[0];
  const int* ei    = (const int*)d_in[1];
  const int* row   = ei;
  const int* col   = ei + NE;
  const int* batch = (const int*)d_in[2];
  const float* emb  = (const float*)d_in[3];
  const float* W1   = (const float*)d_in[4];
  const float* b1   = (const float*)d_in[5];
  const float* W2   = (const float*)d_in[6];
  const float* b2   = (const float*)d_in[7];
  const float* Wout = (const float*)d_in[8];
  const float* bout = (const float*)d_in[9];

  char* ws = (char*)d_ws;
  size_t off = 0;
  auto alloc = [&](size_t bytes) -> void* {
    void* p = (void*)(ws + off);
    off += (bytes + 255) & ~(size_t)255;
    return p;
  };
  int*   cnts   = (int*)alloc((size_t)NN * 4);
  int*   cursor = (int*)alloc((size_t)NN * 4);
  int*   base   = (int*)alloc((size_t)(NN + 1) * 4);
  int*   bsum   = (int*)alloc((size_t)SCAN_NB * 4);
  int*   boff   = (int*)alloc((size_t)SCAN_NB * 4);
  int*   colIdx = (int*)alloc((size_t)NE * 4);
  float* dinv   = (float*)alloc((size_t)NN * 4);
  u16*   whi    = (u16*)alloc((size_t)2 * HID * HID * 2);
  u16*   wlo    = (u16*)alloc((size_t)2 * HID * HID * 2);
  u16*   xbuf   = (u16*)alloc((size_t)NN * HID * 2);
  u16*   gbuf   = (u16*)alloc((size_t)NN * HID * 2);
  (void)ws_size; (void)in_sizes; (void)n_in; (void)out_size;

  const int nbE   = (NE + 255) / 256;
  const int nbN32 = (NN * 32 + 255) / 256;
  const int nbM   = (NN + 63) / 64;  // 782

  // CSR build + dinv (+ weight split)
  k_zero<<<(NN / 4 + 255) / 256, 256, 0, stream>>>(cnts, cursor);
  k_wsplit<<<(2 * HID * HID + 255) / 256, 256, 0, stream>>>(W1, W2, whi, wlo);
  k_count<<<nbE, 256, 0, stream>>>(row, cnts);
  k_scan1<<<SCAN_NB, 256, 0, stream>>>(cnts, bsum);
  k_scan2<<<1, 64, 0, stream>>>(bsum, boff);
  k_scan3<<<SCAN_NB, 256, 0, stream>>>(cnts, boff, base, dinv);
  k_scatter<<<nbE, 256, 0, stream>>>(row, col, base, cursor, colIdx);

  // layer 0 (reads emb[H], packs bf16 in-register) then layer 1 (reads bf16 x)
  k_gemm<true><<<nbM, 256, 0, stream>>>(nullptr, H, emb, whi, wlo, b1, dinv, gbuf);
  k_csr<<<nbN32, 256, 0, stream>>>(base, colIdx, gbuf, dinv, xbuf);
  k_gemm<false><<<nbM, 256, 0, stream>>>(xbuf, nullptr, nullptr,
                                         whi + HID * HID, wlo + HID * HID, b2, dinv, gbuf);
  k_csr<<<nbN32, 256, 0, stream>>>(base, colIdx, gbuf, dinv, xbuf);

  k_pool_out<<<NG, 256, 0, stream>>>(batch, xbuf, Wout, bout, (float*)d_out);
}

// Round 7
// 216.319 us; speedup vs baseline: 1.1467x; 1.1467x over previous
//
#include <hip/hip_runtime.h>

#define NN   50000
#define NE   600000
#define HID  128
#define NOUT_ 64
#define NG   256

#define SCAN_CHUNK 1024
#define SCAN_NB ((NN + SCAN_CHUNK - 1) / SCAN_CHUNK)  // 49

#define NTILES (NN / 16)      // 3125 (exact)
#define TPB    4              // node-tiles per block
#define GEMM_GRID ((NTILES + TPB - 1) / TPB)  // 782

typedef unsigned int u32;
typedef unsigned short u16;
typedef __attribute__((ext_vector_type(8))) short s16x8;  // 8 bf16 (4 VGPRs)
typedef __attribute__((ext_vector_type(4))) float f32x4;

// bf16 helpers (bit ops; accumulate in f32, store RNE bf16)
static __device__ __forceinline__ float bflo(u32 u) { return __uint_as_float(u << 16); }
static __device__ __forceinline__ float bfhi(u32 u) { return __uint_as_float(u & 0xffff0000u); }
static __device__ __forceinline__ u32 pack2bf(float lo, float hi) {
  u32 ul = __float_as_uint(lo), uh = __float_as_uint(hi);
  ul = (ul + 0x7fffu + ((ul >> 16) & 1u)) >> 16;
  uh = (uh + 0x7fffu + ((uh >> 16) & 1u)) >> 16;
  return ul | (uh << 16);
}
static __device__ __forceinline__ u16 bf16rne(float f) {
  u32 u = __float_as_uint(f);
  u = (u + 0x7fffu + ((u >> 16) & 1u)) >> 16;
  return (u16)u;
}

// ---- init / CSR build ------------------------------------------------------

static __global__ void k_zero(int* __restrict__ cnts, int* __restrict__ cursor) {
  int i = (blockIdx.x * 256 + threadIdx.x) * 4;
  if (i < NN) {  // NN % 4 == 0
    *reinterpret_cast<int4*>(&cnts[i]) = make_int4(0, 0, 0, 0);
    *reinterpret_cast<int4*>(&cursor[i]) = make_int4(0, 0, 0, 0);
  }
}

static __global__ void k_count(const int* __restrict__ row, int* __restrict__ cnts) {
  int e = blockIdx.x * 256 + threadIdx.x;
  if (e < NE) atomicAdd(&cnts[row[e]], 1);
}

static __global__ __launch_bounds__(256) void k_scan1(const int* __restrict__ cnts,
                                                      int* __restrict__ bsum) {
  __shared__ int red[4];
  const int b = blockIdx.x, tid = threadIdx.x;
  const int start = b * SCAN_CHUNK + tid * 4;
  int s = 0;
#pragma unroll
  for (int i = 0; i < 4; ++i) {
    int idx = start + i;
    if (idx < NN) s += cnts[idx];
  }
#pragma unroll
  for (int o = 1; o < 64; o <<= 1) s += __shfl_xor(s, o);
  if ((tid & 63) == 0) red[tid >> 6] = s;
  __syncthreads();
  if (tid == 0) bsum[b] = red[0] + red[1] + red[2] + red[3];
}

static __global__ void k_scan2(const int* __restrict__ bsum, int* __restrict__ boff) {
  const int tid = threadIdx.x;  // 64 threads
  int orig = (tid < SCAN_NB) ? bsum[tid] : 0;
  int v = orig;
#pragma unroll
  for (int o = 1; o < 64; o <<= 1) {
    int u = __shfl_up(v, o);
    if (tid >= o) v += u;
  }
  if (tid < SCAN_NB) boff[tid] = v - orig;
}

static __global__ __launch_bounds__(256) void k_scan3(const int* __restrict__ cnts,
                                                      const int* __restrict__ boff,
                                                      int* __restrict__ base,
                                                      float* __restrict__ dinv) {
  __shared__ int wsum[4];
  const int b = blockIdx.x, tid = threadIdx.x;
  const int start = b * SCAN_CHUNK + tid * 4;
  int c[4];
  int s = 0;
#pragma unroll
  for (int i = 0; i < 4; ++i) {
    int idx = start + i;
    c[i] = (idx < NN) ? cnts[idx] : 0;
    s += c[i];
  }
  const int orig = s;
  const int lane = tid & 63, w = tid >> 6;
#pragma unroll
  for (int o = 1; o < 64; o <<= 1) {
    int u = __shfl_up(s, o);
    if (lane >= o) s += u;
  }
  if (lane == 63) wsum[w] = s;
  __syncthreads();
  int ex = s - orig + boff[b];
  for (int i = 0; i < w; ++i) ex += wsum[i];
#pragma unroll
  for (int i = 0; i < 4; ++i) {
    int idx = start + i;
    if (idx < NN) {
      base[idx] = ex;
      ex += c[i];
      dinv[idx] = rsqrtf((float)(c[i] + 1));  // +1 self-loop
    }
  }
  if (b == 0 && tid == 0) base[NN] = NE;
}

static __global__ void k_scatter(const int* __restrict__ row, const int* __restrict__ col,
                                 const int* __restrict__ base, int* __restrict__ cursor,
                                 int* __restrict__ colIdx) {
  int e = blockIdx.x * 256 + threadIdx.x;
  if (e >= NE) return;
  int r = row[e];
  int pos = base[r] + atomicAdd(&cursor[r], 1);
  colIdx[pos] = col[e];
}

// ---- weight split: W -> Whi + Wlo (bf16 each), error ~2^-17 ----------------

static __global__ void k_wsplit(const float* __restrict__ W1, const float* __restrict__ W2,
                                u16* __restrict__ whi, u16* __restrict__ wlo) {
  int i = blockIdx.x * 256 + threadIdx.x;  // 0..32767
  if (i >= 2 * HID * HID) return;
  float w = (i < HID * HID) ? W1[i] : W2[i - HID * HID];
  u16 hi = bf16rne(w);
  float fhi = __uint_as_float(((u32)hi) << 16);
  whi[i] = hi;
  wlo[i] = bf16rne(w - fhi);
}

// ---- MFMA GEMM: g(bf16) = (src @ W^T + b) * dinv[row] ----------------------
// Operand swap: A = W-tile (features), B = x-tile (nodes). Per-wave-resident
// W frags for 2 feature-tiles; stream node-tiles. D: col(l&15)=node,
// row((l>>4)*4+reg)=feature -> lane holds 4 consecutive features of 1 node.

template <bool FIRST>
static __global__ __launch_bounds__(256) void k_gemm(
    const u16* __restrict__ x, const int* __restrict__ H,
    const float* __restrict__ emb,
    const u16* __restrict__ whi, const u16* __restrict__ wlo,
    const float* __restrict__ bias, const float* __restrict__ dinv,
    u16* __restrict__ g) {
  const int tid = threadIdx.x;
  const int wv = tid >> 6;        // wave 0..3 -> feature-tiles 2wv, 2wv+1
  const int l = tid & 63;
  const int l16 = l & 15, g4 = l >> 4;

  // resident W fragments (A-operand): wh/wl[tt][s]
  s16x8 wh[2][4], wl[2][4];
  float4 bb[2];
#pragma unroll
  for (int tt = 0; tt < 2; ++tt) {
    const int trow = (wv * 2 + tt) * 16 + l16;
#pragma unroll
    for (int s = 0; s < 4; ++s) {
      const int koff = s * 32 + g4 * 8;
      wh[tt][s] = *reinterpret_cast<const s16x8*>(&whi[(size_t)trow * HID + koff]);
      wl[tt][s] = *reinterpret_cast<const s16x8*>(&wlo[(size_t)trow * HID + koff]);
    }
    bb[tt] = *reinterpret_cast<const float4*>(&bias[(wv * 2 + tt) * 16 + g4 * 4]);
  }

  for (int it = 0; it < TPB; ++it) {
    const int tile = blockIdx.x * TPB + it;
    if (tile >= NTILES) return;
    const int n = tile * 16 + l16;  // this lane's node (NN = 16*NTILES exactly)

    // B-operand fragments: x[n] (bf16) or emb[H[n]] (f32, packed in-register)
    s16x8 xf[4];
    if (FIRST) {
      const int h = H[n];
      const float* ep = &emb[(size_t)h * HID];
#pragma unroll
      for (int s = 0; s < 4; ++s) {
        const int koff = s * 32 + g4 * 8;
        float4 u0 = *reinterpret_cast<const float4*>(ep + koff);
        float4 u1 = *reinterpret_cast<const float4*>(ep + koff + 4);
        union { s16x8 v; u32 w[4]; } au;
        au.w[0] = pack2bf(u0.x, u0.y);
        au.w[1] = pack2bf(u0.z, u0.w);
        au.w[2] = pack2bf(u1.x, u1.y);
        au.w[3] = pack2bf(u1.z, u1.w);
        xf[s] = au.v;
      }
    } else {
#pragma unroll
      for (int s = 0; s < 4; ++s)
        xf[s] = *reinterpret_cast<const s16x8*>(&x[(size_t)n * HID + s * 32 + g4 * 8]);
    }
    const float dv = dinv[n];

    f32x4 acc[2];
    acc[0] = (f32x4){0.f, 0.f, 0.f, 0.f};
    acc[1] = (f32x4){0.f, 0.f, 0.f, 0.f};
#pragma unroll
    for (int s = 0; s < 4; ++s) {
#pragma unroll
      for (int tt = 0; tt < 2; ++tt) {
        acc[tt] = __builtin_amdgcn_mfma_f32_16x16x32_bf16(wh[tt][s], xf[s], acc[tt], 0, 0, 0);
        acc[tt] = __builtin_amdgcn_mfma_f32_16x16x32_bf16(wl[tt][s], xf[s], acc[tt], 0, 0, 0);
      }
    }

    // epilogue: features (wv*2+tt)*16 + g4*4 + j for node n; 8B store per tile
#pragma unroll
    for (int tt = 0; tt < 2; ++tt) {
      const float v0 = (acc[tt][0] + bb[tt].x) * dv;
      const float v1 = (acc[tt][1] + bb[tt].y) * dv;
      const float v2 = (acc[tt][2] + bb[tt].z) * dv;
      const float v3 = (acc[tt][3] + bb[tt].w) * dv;
      *reinterpret_cast<uint2*>(&g[(size_t)n * HID + (wv * 2 + tt) * 16 + g4 * 4]) =
          make_uint2(pack2bf(v0, v1), pack2bf(v2, v3));
    }
  }
}

// x[node](bf16) = relu( dinv[node] * ( g[node] + sum_{c in adj(node)} g[c] ) )
static __global__ void k_csr(const int* __restrict__ base, const int* __restrict__ colIdx,
                             const u16* __restrict__ g, const float* __restrict__ dinv,
                             u16* __restrict__ x) {
  int t = blockIdx.x * 256 + threadIdx.x;
  int node = t >> 5;
  if (node >= NN) return;
  const int lane2 = (t & 31) * 2;  // u32 index within row (HID/2 = 64 u32)
  const u32* gw = (const u32*)g;

  uint2 v = *reinterpret_cast<const uint2*>(gw + (size_t)node * 64 + lane2);  // self
  float a0 = bflo(v.x), a1 = bfhi(v.x), a2 = bflo(v.y), a3 = bfhi(v.y);

  const int s = base[node], e = base[node + 1];
  int i = s;
  for (; i + 4 <= e; i += 4) {
    int c0 = colIdx[i], c1 = colIdx[i + 1], c2 = colIdx[i + 2], c3 = colIdx[i + 3];
    uint2 w0 = *reinterpret_cast<const uint2*>(gw + (size_t)c0 * 64 + lane2);
    uint2 w1 = *reinterpret_cast<const uint2*>(gw + (size_t)c1 * 64 + lane2);
    uint2 w2 = *reinterpret_cast<const uint2*>(gw + (size_t)c2 * 64 + lane2);
    uint2 w3 = *reinterpret_cast<const uint2*>(gw + (size_t)c3 * 64 + lane2);
    a0 += bflo(w0.x) + bflo(w1.x) + bflo(w2.x) + bflo(w3.x);
    a1 += bfhi(w0.x) + bfhi(w1.x) + bfhi(w2.x) + bfhi(w3.x);
    a2 += bflo(w0.y) + bflo(w1.y) + bflo(w2.y) + bflo(w3.y);
    a3 += bfhi(w0.y) + bfhi(w1.y) + bfhi(w2.y) + bfhi(w3.y);
  }
  for (; i < e; ++i) {
    uint2 w = *reinterpret_cast<const uint2*>(gw + (size_t)colIdx[i] * 64 + lane2);
    a0 += bflo(w.x); a1 += bfhi(w.x); a2 += bflo(w.y); a3 += bfhi(w.y);
  }
  float d = dinv[node];
  a0 = fmaxf(a0 * d, 0.f);
  a1 = fmaxf(a1 * d, 0.f);
  a2 = fmaxf(a2 * d, 0.f);
  a3 = fmaxf(a3 * d, 0.f);
  *reinterpret_cast<uint2*>((u32*)x + (size_t)node * 64 + lane2) =
      make_uint2(pack2bf(a0, a1), pack2bf(a2, a3));
}

// ---- fused mean-pool + head (batch is SORTED) ------------------------------

static __device__ __forceinline__ int lb(const int* __restrict__ b, int n, int v) {
  int lo = 0, hi = n;
  while (lo < hi) { int m = (lo + hi) >> 1; if (b[m] < v) lo = m + 1; else hi = m; }
  return lo;
}

static __global__ __launch_bounds__(256) void k_pool_out(
    const int* __restrict__ batch, const u16* __restrict__ x,
    const float* __restrict__ Wout, const float* __restrict__ bout,
    float* __restrict__ out) {
  const int g = blockIdx.x;
  const int tid = threadIdx.x;
  const int s = lb(batch, NN, g);
  const int e = lb(batch, NN, g + 1);
  const float inv = 1.0f / fmaxf((float)(e - s), 1.0f);

  const int d = tid & 127;
  const int half = tid >> 7;
  float acc = 0.f;
  for (int i = s + half; i < e; i += 2)
    acc += __uint_as_float(((u32)x[(size_t)i * HID + d]) << 16);

  __shared__ float tmp[256];
  __shared__ float pooled[HID];
  tmp[tid] = acc;
  __syncthreads();
  if (tid < HID) pooled[tid] = (tmp[tid] + tmp[tid + HID]) * inv;
  __syncthreads();

  const int o = tid >> 2, q = tid & 3;
  const float* wrow = &Wout[o * HID + q * 32];
  const float* prow = &pooled[q * 32];
  float a = 0.f;
#pragma unroll
  for (int k = 0; k < 32; k += 4) {
    float4 p = *reinterpret_cast<const float4*>(&prow[k]);
    float4 w = *reinterpret_cast<const float4*>(&wrow[k]);
    a += p.x * w.x + p.y * w.y + p.z * w.z + p.w * w.w;
  }
  a += __shfl_xor(a, 1);
  a += __shfl_xor(a, 2);
  if (q == 0) out[g * NOUT_ + o] = a + bout[o];
}

extern "C" void kernel_launch(void* const* d_in, const int* in_sizes, int n_in,
                              void* d_out, int out_size, void* d_ws, size_t ws_size,
                              hipStream_t stream) {
  const int* H     = (const int*)d_in[0];
  const int* ei    = (const int*)d_in[1];
  const int* row   = ei;
  const int* col   = ei + NE;
  const int* batch = (const int*)d_in[2];
  const float* emb  = (const float*)d_in[3];
  const float* W1   = (const float*)d_in[4];
  const float* b1   = (const float*)d_in[5];
  const float* W2   = (const float*)d_in[6];
  const float* b2   = (const float*)d_in[7];
  const float* Wout = (const float*)d_in[8];
  const float* bout = (const float*)d_in[9];

  char* ws = (char*)d_ws;
  size_t off = 0;
  auto alloc = [&](size_t bytes) -> void* {
    void* p = (void*)(ws + off);
    off += (bytes + 255) & ~(size_t)255;
    return p;
  };
  int*   cnts   = (int*)alloc((size_t)NN * 4);
  int*   cursor = (int*)alloc((size_t)NN * 4);
  int*   base   = (int*)alloc((size_t)(NN + 1) * 4);
  int*   bsum   = (int*)alloc((size_t)SCAN_NB * 4);
  int*   boff   = (int*)alloc((size_t)SCAN_NB * 4);
  int*   colIdx = (int*)alloc((size_t)NE * 4);
  float* dinv   = (float*)alloc((size_t)NN * 4);
  u16*   whi    = (u16*)alloc((size_t)2 * HID * HID * 2);
  u16*   wlo    = (u16*)alloc((size_t)2 * HID * HID * 2);
  u16*   xbuf   = (u16*)alloc((size_t)NN * HID * 2);
  u16*   gbuf   = (u16*)alloc((size_t)NN * HID * 2);
  (void)ws_size; (void)in_sizes; (void)n_in; (void)out_size;

  const int nbE   = (NE + 255) / 256;
  const int nbN32 = (NN * 32 + 255) / 256;

  // CSR build + dinv (+ weight split)
  k_zero<<<(NN / 4 + 255) / 256, 256, 0, stream>>>(cnts, cursor);
  k_wsplit<<<(2 * HID * HID + 255) / 256, 256, 0, stream>>>(W1, W2, whi, wlo);
  k_count<<<nbE, 256, 0, stream>>>(row, cnts);
  k_scan1<<<SCAN_NB, 256, 0, stream>>>(cnts, bsum);
  k_scan2<<<1, 64, 0, stream>>>(bsum, boff);
  k_scan3<<<SCAN_NB, 256, 0, stream>>>(cnts, boff, base, dinv);
  k_scatter<<<nbE, 256, 0, stream>>>(row, col, base, cursor, colIdx);

  // layer 0 (reads emb[H], packs bf16 in-register) then layer 1 (reads bf16 x)
  k_gemm<true><<<GEMM_GRID, 256, 0, stream>>>(nullptr, H, emb, whi, wlo, b1, dinv, gbuf);
  k_csr<<<nbN32, 256, 0, stream>>>(base, colIdx, gbuf, dinv, xbuf);
  k_gemm<false><<<GEMM_GRID, 256, 0, stream>>>(xbuf, nullptr, nullptr,
                                               whi + HID * HID, wlo + HID * HID, b2, dinv, gbuf);
  k_csr<<<nbN32, 256, 0, stream>>>(base, colIdx, gbuf, dinv, xbuf);

  k_pool_out<<<NG, 256, 0, stream>>>(batch, xbuf, Wout, bout, (float*)d_out);
}

// Round 8
// 193.419 us; speedup vs baseline: 1.2825x; 1.1184x over previous
//
#include <hip/hip_runtime.h>

#define NN   50000
#define NE   600000
#define HID  128
#define NOUT_ 64
#define NG   256
#define NT   100   // NUM_TYPES

#define SCAN_CHUNK 1024
#define SCAN_NB ((NN + SCAN_CHUNK - 1) / SCAN_CHUNK)  // 49

#define NTILES (NN / 16)      // 3125 (exact)
#define TPB    4              // node-tiles per block
#define GEMM_GRID ((NTILES + TPB - 1) / TPB)  // 782

typedef unsigned int u32;
typedef unsigned short u16;
typedef __attribute__((ext_vector_type(8))) short s16x8;  // 8 bf16 (4 VGPRs)
typedef __attribute__((ext_vector_type(4))) float f32x4;

// bf16 helpers (bit ops; accumulate in f32, store RNE bf16)
static __device__ __forceinline__ float bflo(u32 u) { return __uint_as_float(u << 16); }
static __device__ __forceinline__ float bfhi(u32 u) { return __uint_as_float(u & 0xffff0000u); }
static __device__ __forceinline__ u32 pack2bf(float lo, float hi) {
  u32 ul = __float_as_uint(lo), uh = __float_as_uint(hi);
  ul = (ul + 0x7fffu + ((ul >> 16) & 1u)) >> 16;
  uh = (uh + 0x7fffu + ((uh >> 16) & 1u)) >> 16;
  return ul | (uh << 16);
}
static __device__ __forceinline__ u16 bf16rne(float f) {
  u32 u = __float_as_uint(f);
  u = (u + 0x7fffu + ((u >> 16) & 1u)) >> 16;
  return (u16)u;
}

// ---- init / CSR build ------------------------------------------------------

static __global__ void k_zero(int* __restrict__ cnts, int* __restrict__ cursor) {
  int i = (blockIdx.x * 256 + threadIdx.x) * 4;
  if (i < NN) {  // NN % 4 == 0
    *reinterpret_cast<int4*>(&cnts[i]) = make_int4(0, 0, 0, 0);
    *reinterpret_cast<int4*>(&cursor[i]) = make_int4(0, 0, 0, 0);
  }
}

static __global__ void k_count(const int* __restrict__ row, int* __restrict__ cnts) {
  int e = blockIdx.x * 256 + threadIdx.x;
  if (e < NE) atomicAdd(&cnts[row[e]], 1);
}

static __global__ __launch_bounds__(256) void k_scan1(const int* __restrict__ cnts,
                                                      int* __restrict__ bsum) {
  __shared__ int red[4];
  const int b = blockIdx.x, tid = threadIdx.x;
  const int start = b * SCAN_CHUNK + tid * 4;
  int s = 0;
#pragma unroll
  for (int i = 0; i < 4; ++i) {
    int idx = start + i;
    if (idx < NN) s += cnts[idx];
  }
#pragma unroll
  for (int o = 1; o < 64; o <<= 1) s += __shfl_xor(s, o);
  if ((tid & 63) == 0) red[tid >> 6] = s;
  __syncthreads();
  if (tid == 0) bsum[b] = red[0] + red[1] + red[2] + red[3];
}

static __global__ void k_scan2(const int* __restrict__ bsum, int* __restrict__ boff) {
  const int tid = threadIdx.x;  // 64 threads
  int orig = (tid < SCAN_NB) ? bsum[tid] : 0;
  int v = orig;
#pragma unroll
  for (int o = 1; o < 64; o <<= 1) {
    int u = __shfl_up(v, o);
    if (tid >= o) v += u;
  }
  if (tid < SCAN_NB) boff[tid] = v - orig;
}

static __global__ __launch_bounds__(256) void k_scan3(const int* __restrict__ cnts,
                                                      const int* __restrict__ boff,
                                                      int* __restrict__ base,
                                                      float* __restrict__ dinv) {
  __shared__ int wsum[4];
  const int b = blockIdx.x, tid = threadIdx.x;
  const int start = b * SCAN_CHUNK + tid * 4;
  int c[4];
  int s = 0;
#pragma unroll
  for (int i = 0; i < 4; ++i) {
    int idx = start + i;
    c[i] = (idx < NN) ? cnts[idx] : 0;
    s += c[i];
  }
  const int orig = s;
  const int lane = tid & 63, w = tid >> 6;
#pragma unroll
  for (int o = 1; o < 64; o <<= 1) {
    int u = __shfl_up(s, o);
    if (lane >= o) s += u;
  }
  if (lane == 63) wsum[w] = s;
  __syncthreads();
  int ex = s - orig + boff[b];
  for (int i = 0; i < w; ++i) ex += wsum[i];
#pragma unroll
  for (int i = 0; i < 4; ++i) {
    int idx = start + i;
    if (idx < NN) {
      base[idx] = ex;
      ex += c[i];
      dinv[idx] = rsqrtf((float)(c[i] + 1));  // +1 self-loop
    }
  }
  if (b == 0 && tid == 0) base[NN] = NE;
}

static __global__ void k_scatter(const int* __restrict__ row, const int* __restrict__ col,
                                 const int* __restrict__ base, int* __restrict__ cursor,
                                 int* __restrict__ colIdx) {
  int e = blockIdx.x * 256 + threadIdx.x;
  if (e >= NE) return;
  int r = row[e];
  int pos = base[r] + atomicAdd(&cursor[r], 1);
  colIdx[pos] = col[e];
}

// ---- weight split (layer 2 only): W2 -> Whi + Wlo (bf16 each) --------------

static __global__ void k_wsplit(const float* __restrict__ W2,
                                u16* __restrict__ whi, u16* __restrict__ wlo) {
  int i = blockIdx.x * 256 + threadIdx.x;
  if (i >= HID * HID) return;
  float w = W2[i];
  u16 hi = bf16rne(w);
  float fhi = __uint_as_float(((u32)hi) << 16);
  whi[i] = hi;
  wlo[i] = bf16rne(w - fhi);
}

// ---- layer-0 table: ew[t] = emb[t] @ W1^T + b1  (100 x 128, f32, 51 KB) ----

static __global__ __launch_bounds__(128) void k_ew(
    const float* __restrict__ emb, const float* __restrict__ W1,
    const float* __restrict__ b1, float* __restrict__ ew) {
  __shared__ float er[HID];
  const int t = blockIdx.x, o = threadIdx.x;
  er[o] = emb[(size_t)t * HID + o];
  __syncthreads();
  const float* wr = &W1[(size_t)o * HID];
  float acc = 0.f;
#pragma unroll
  for (int k = 0; k < HID; k += 4) {
    float4 w = *reinterpret_cast<const float4*>(&wr[k]);
    acc += er[k] * w.x + er[k + 1] * w.y + er[k + 2] * w.z + er[k + 3] * w.w;
  }
  ew[(size_t)t * HID + o] = acc + b1[o];
}

// ---- layer-0 fused GEMM+aggregate:
// x1[n] = relu( dinv[n] * ( dinv[n]*ew[H[n]] + sum_c dinv[c]*ew[H[c]] ) )
static __global__ void k_csr0(const int* __restrict__ base, const int* __restrict__ colIdx,
                              const int* __restrict__ H, const float* __restrict__ ew,
                              const float* __restrict__ dinv, u16* __restrict__ x) {
  int t = blockIdx.x * 256 + threadIdx.x;
  int node = t >> 5;
  if (node >= NN) return;
  const int lane = t & 31;
  const int j = lane * 4;  // f32 dims j..j+3

  const float dn = dinv[node];
  float4 wn = *reinterpret_cast<const float4*>(&ew[(size_t)H[node] * HID + j]);
  float a0 = dn * wn.x, a1 = dn * wn.y, a2 = dn * wn.z, a3 = dn * wn.w;

  const int s = base[node], e = base[node + 1];
  int i = s;
  for (; i + 2 <= e; i += 2) {
    int c0 = colIdx[i], c1 = colIdx[i + 1];
    float d0 = dinv[c0], d1 = dinv[c1];
    float4 w0 = *reinterpret_cast<const float4*>(&ew[(size_t)H[c0] * HID + j]);
    float4 w1 = *reinterpret_cast<const float4*>(&ew[(size_t)H[c1] * HID + j]);
    a0 += d0 * w0.x + d1 * w1.x;
    a1 += d0 * w0.y + d1 * w1.y;
    a2 += d0 * w0.z + d1 * w1.z;
    a3 += d0 * w0.w + d1 * w1.w;
  }
  if (i < e) {
    int c0 = colIdx[i];
    float d0 = dinv[c0];
    float4 w0 = *reinterpret_cast<const float4*>(&ew[(size_t)H[c0] * HID + j]);
    a0 += d0 * w0.x; a1 += d0 * w0.y; a2 += d0 * w0.z; a3 += d0 * w0.w;
  }
  a0 = fmaxf(a0 * dn, 0.f);
  a1 = fmaxf(a1 * dn, 0.f);
  a2 = fmaxf(a2 * dn, 0.f);
  a3 = fmaxf(a3 * dn, 0.f);
  *reinterpret_cast<uint2*>((u32*)x + (size_t)node * 64 + lane * 2) =
      make_uint2(pack2bf(a0, a1), pack2bf(a2, a3));
}

// ---- MFMA GEMM (layer 2): g(bf16) = (x @ W2^T + b2) * dinv[row] ------------
// A = W-tile (features, wave-resident), B = x-tile (nodes, streamed).
// D: col(l&15)=node, row((l>>4)*4+reg)=feature.

static __global__ __launch_bounds__(256) void k_gemm(
    const u16* __restrict__ x,
    const u16* __restrict__ whi, const u16* __restrict__ wlo,
    const float* __restrict__ bias, const float* __restrict__ dinv,
    u16* __restrict__ g) {
  const int tid = threadIdx.x;
  const int wv = tid >> 6;        // wave 0..3 -> feature-tiles 2wv, 2wv+1
  const int l = tid & 63;
  const int l16 = l & 15, g4 = l >> 4;

  s16x8 wh[2][4], wl[2][4];
  float4 bb[2];
#pragma unroll
  for (int tt = 0; tt < 2; ++tt) {
    const int trow = (wv * 2 + tt) * 16 + l16;
#pragma unroll
    for (int s = 0; s < 4; ++s) {
      const int koff = s * 32 + g4 * 8;
      wh[tt][s] = *reinterpret_cast<const s16x8*>(&whi[(size_t)trow * HID + koff]);
      wl[tt][s] = *reinterpret_cast<const s16x8*>(&wlo[(size_t)trow * HID + koff]);
    }
    bb[tt] = *reinterpret_cast<const float4*>(&bias[(wv * 2 + tt) * 16 + g4 * 4]);
  }

  for (int it = 0; it < TPB; ++it) {
    const int tile = blockIdx.x * TPB + it;
    if (tile >= NTILES) return;
    const int n = tile * 16 + l16;

    s16x8 xf[4];
#pragma unroll
    for (int s = 0; s < 4; ++s)
      xf[s] = *reinterpret_cast<const s16x8*>(&x[(size_t)n * HID + s * 32 + g4 * 8]);
    const float dv = dinv[n];

    f32x4 acc[2];
    acc[0] = (f32x4){0.f, 0.f, 0.f, 0.f};
    acc[1] = (f32x4){0.f, 0.f, 0.f, 0.f};
#pragma unroll
    for (int s = 0; s < 4; ++s) {
#pragma unroll
      for (int tt = 0; tt < 2; ++tt) {
        acc[tt] = __builtin_amdgcn_mfma_f32_16x16x32_bf16(wh[tt][s], xf[s], acc[tt], 0, 0, 0);
        acc[tt] = __builtin_amdgcn_mfma_f32_16x16x32_bf16(wl[tt][s], xf[s], acc[tt], 0, 0, 0);
      }
    }

#pragma unroll
    for (int tt = 0; tt < 2; ++tt) {
      const float v0 = (acc[tt][0] + bb[tt].x) * dv;
      const float v1 = (acc[tt][1] + bb[tt].y) * dv;
      const float v2 = (acc[tt][2] + bb[tt].z) * dv;
      const float v3 = (acc[tt][3] + bb[tt].w) * dv;
      *reinterpret_cast<uint2*>(&g[(size_t)n * HID + (wv * 2 + tt) * 16 + g4 * 4]) =
          make_uint2(pack2bf(v0, v1), pack2bf(v2, v3));
    }
  }
}

// x[node](bf16) = relu( dinv[node] * ( g[node] + sum_{c in adj(node)} g[c] ) )
static __global__ void k_csr(const int* __restrict__ base, const int* __restrict__ colIdx,
                             const u16* __restrict__ g, const float* __restrict__ dinv,
                             u16* __restrict__ x) {
  int t = blockIdx.x * 256 + threadIdx.x;
  int node = t >> 5;
  if (node >= NN) return;
  const int lane2 = (t & 31) * 2;  // u32 index within row (HID/2 = 64 u32)
  const u32* gw = (const u32*)g;

  uint2 v = *reinterpret_cast<const uint2*>(gw + (size_t)node * 64 + lane2);  // self
  float a0 = bflo(v.x), a1 = bfhi(v.x), a2 = bflo(v.y), a3 = bfhi(v.y);

  const int s = base[node], e = base[node + 1];
  int i = s;
  for (; i + 4 <= e; i += 4) {
    int c0 = colIdx[i], c1 = colIdx[i + 1], c2 = colIdx[i + 2], c3 = colIdx[i + 3];
    uint2 w0 = *reinterpret_cast<const uint2*>(gw + (size_t)c0 * 64 + lane2);
    uint2 w1 = *reinterpret_cast<const uint2*>(gw + (size_t)c1 * 64 + lane2);
    uint2 w2 = *reinterpret_cast<const uint2*>(gw + (size_t)c2 * 64 + lane2);
    uint2 w3 = *reinterpret_cast<const uint2*>(gw + (size_t)c3 * 64 + lane2);
    a0 += bflo(w0.x) + bflo(w1.x) + bflo(w2.x) + bflo(w3.x);
    a1 += bfhi(w0.x) + bfhi(w1.x) + bfhi(w2.x) + bfhi(w3.x);
    a2 += bflo(w0.y) + bflo(w1.y) + bflo(w2.y) + bflo(w3.y);
    a3 += bfhi(w0.y) + bfhi(w1.y) + bfhi(w2.y) + bfhi(w3.y);
  }
  for (; i < e; ++i) {
    uint2 w = *reinterpret_cast<const uint2*>(gw + (size_t)colIdx[i] * 64 + lane2);
    a0 += bflo(w.x); a1 += bfhi(w.x); a2 += bflo(w.y); a3 += bfhi(w.y);
  }
  float d = dinv[node];
  a0 = fmaxf(a0 * d, 0.f);
  a1 = fmaxf(a1 * d, 0.f);
  a2 = fmaxf(a2 * d, 0.f);
  a3 = fmaxf(a3 * d, 0.f);
  *reinterpret_cast<uint2*>((u32*)x + (size_t)node * 64 + lane2) =
      make_uint2(pack2bf(a0, a1), pack2bf(a2, a3));
}

// ---- fused mean-pool + head (batch is SORTED) ------------------------------

static __device__ __forceinline__ int lb(const int* __restrict__ b, int n, int v) {
  int lo = 0, hi = n;
  while (lo < hi) { int m = (lo + hi) >> 1; if (b[m] < v) lo = m + 1; else hi = m; }
  return lo;
}

static __global__ __launch_bounds__(256) void k_pool_out(
    const int* __restrict__ batch, const u16* __restrict__ x,
    const float* __restrict__ Wout, const float* __restrict__ bout,
    float* __restrict__ out) {
  const int g = blockIdx.x;
  const int tid = threadIdx.x;
  const int s = lb(batch, NN, g);
  const int e = lb(batch, NN, g + 1);
  const float inv = 1.0f / fmaxf((float)(e - s), 1.0f);

  const int d = tid & 127;
  const int half = tid >> 7;
  float acc = 0.f;
  for (int i = s + half; i < e; i += 2)
    acc += __uint_as_float(((u32)x[(size_t)i * HID + d]) << 16);

  __shared__ float tmp[256];
  __shared__ float pooled[HID];
  tmp[tid] = acc;
  __syncthreads();
  if (tid < HID) pooled[tid] = (tmp[tid] + tmp[tid + HID]) * inv;
  __syncthreads();

  const int o = tid >> 2, q = tid & 3;
  const float* wrow = &Wout[o * HID + q * 32];
  const float* prow = &pooled[q * 32];
  float a = 0.f;
#pragma unroll
  for (int k = 0; k < 32; k += 4) {
    float4 p = *reinterpret_cast<const float4*>(&prow[k]);
    float4 w = *reinterpret_cast<const float4*>(&wrow[k]);
    a += p.x * w.x + p.y * w.y + p.z * w.z + p.w * w.w;
  }
  a += __shfl_xor(a, 1);
  a += __shfl_xor(a, 2);
  if (q == 0) out[g * NOUT_ + o] = a + bout[o];
}

extern "C" void kernel_launch(void* const* d_in, const int* in_sizes, int n_in,
                              void* d_out, int out_size, void* d_ws, size_t ws_size,
                              hipStream_t stream) {
  const int* H     = (const int*)d_in[0];
  const int* ei    = (const int*)d_in[1];
  const int* row   = ei;
  const int* col   = ei + NE;
  const int* batch = (const int*)d_in[2];
  const float* emb  = (const float*)d_in[3];
  const float* W1   = (const float*)d_in[4];
  const float* b1   = (const float*)d_in[5];
  const float* W2   = (const float*)d_in[6];
  const float* b2   = (const float*)d_in[7];
  const float* Wout = (const float*)d_in[8];
  const float* bout = (const float*)d_in[9];

  char* ws = (char*)d_ws;
  size_t off = 0;
  auto alloc = [&](size_t bytes) -> void* {
    void* p = (void*)(ws + off);
    off += (bytes + 255) & ~(size_t)255;
    return p;
  };
  int*   cnts   = (int*)alloc((size_t)NN * 4);
  int*   cursor = (int*)alloc((size_t)NN * 4);
  int*   base   = (int*)alloc((size_t)(NN + 1) * 4);
  int*   bsum   = (int*)alloc((size_t)SCAN_NB * 4);
  int*   boff   = (int*)alloc((size_t)SCAN_NB * 4);
  int*   colIdx = (int*)alloc((size_t)NE * 4);
  float* dinv   = (float*)alloc((size_t)NN * 4);
  float* ew     = (float*)alloc((size_t)NT * HID * 4);
  u16*   whi    = (u16*)alloc((size_t)HID * HID * 2);
  u16*   wlo    = (u16*)alloc((size_t)HID * HID * 2);
  u16*   xbuf   = (u16*)alloc((size_t)NN * HID * 2);
  u16*   gbuf   = (u16*)alloc((size_t)NN * HID * 2);
  (void)ws_size; (void)in_sizes; (void)n_in; (void)out_size;

  const int nbE   = (NE + 255) / 256;
  const int nbN32 = (NN * 32 + 255) / 256;

  // CSR build + dinv + layer-0 table + W2 split
  k_zero<<<(NN / 4 + 255) / 256, 256, 0, stream>>>(cnts, cursor);
  k_wsplit<<<(HID * HID + 255) / 256, 256, 0, stream>>>(W2, whi, wlo);
  k_ew<<<NT, 128, 0, stream>>>(emb, W1, b1, ew);
  k_count<<<nbE, 256, 0, stream>>>(row, cnts);
  k_scan1<<<SCAN_NB, 256, 0, stream>>>(cnts, bsum);
  k_scan2<<<1, 64, 0, stream>>>(bsum, boff);
  k_scan3<<<SCAN_NB, 256, 0, stream>>>(cnts, boff, base, dinv);
  k_scatter<<<nbE, 256, 0, stream>>>(row, col, base, cursor, colIdx);

  // layer 0: fully fused (table gather + aggregate + relu)
  k_csr0<<<nbN32, 256, 0, stream>>>(base, colIdx, H, ew, dinv, xbuf);
  // layer 1: MFMA GEMM + aggregate
  k_gemm<<<GEMM_GRID, 256, 0, stream>>>(xbuf, whi, wlo, b2, dinv, gbuf);
  k_csr<<<nbN32, 256, 0, stream>>>(base, colIdx, gbuf, dinv, xbuf);

  k_pool_out<<<NG, 256, 0, stream>>>(batch, xbuf, Wout, bout, (float*)d_out);
}

// Round 9
// 172.474 us; speedup vs baseline: 1.4382x; 1.1214x over previous
//
#include <hip/hip_runtime.h>

#define NN   50000
#define NE   600000
#define HID  128
#define NOUT_ 64
#define NG   256
#define NT   100   // NUM_TYPES

#define NN_P   50048                 // padded to 3128 full 16-node tiles
#define NTILES (NN_P / 16)           // 3128
#define TPB    4                     // node-tiles per block
#define GEMM_GRID (NTILES / TPB)     // 782

#define SCAN_CHUNK 1024
#define SCAN_NB ((NN + SCAN_CHUNK - 1) / SCAN_CHUNK)  // 49

typedef unsigned int u32;
typedef unsigned short u16;
typedef __attribute__((ext_vector_type(8))) short s16x8;  // 8 bf16 (4 VGPRs)
typedef __attribute__((ext_vector_type(4))) float f32x4;

// bf16 helpers (bit ops; accumulate in f32, store RNE bf16)
static __device__ __forceinline__ float bflo(u32 u) { return __uint_as_float(u << 16); }
static __device__ __forceinline__ float bfhi(u32 u) { return __uint_as_float(u & 0xffff0000u); }
static __device__ __forceinline__ u32 pack2bf(float lo, float hi) {
  u32 ul = __float_as_uint(lo), uh = __float_as_uint(hi);
  ul = (ul + 0x7fffu + ((ul >> 16) & 1u)) >> 16;
  uh = (uh + 0x7fffu + ((uh >> 16) & 1u)) >> 16;
  return ul | (uh << 16);
}
static __device__ __forceinline__ u16 bf16rne(float f) {
  u32 u = __float_as_uint(f);
  u = (u + 0x7fffu + ((u >> 16) & 1u)) >> 16;
  return (u16)u;
}

// ---- init / CSR build ------------------------------------------------------

static __global__ void k_zero(int* __restrict__ cnts, int* __restrict__ cursor) {
  int i = (blockIdx.x * 256 + threadIdx.x) * 4;
  if (i < NN) {  // NN % 4 == 0
    *reinterpret_cast<int4*>(&cnts[i]) = make_int4(0, 0, 0, 0);
    *reinterpret_cast<int4*>(&cursor[i]) = make_int4(0, 0, 0, 0);
  }
}

static __global__ void k_count(const int* __restrict__ row, int* __restrict__ cnts) {
  int e = blockIdx.x * 256 + threadIdx.x;
  if (e < NE) atomicAdd(&cnts[row[e]], 1);
}

static __global__ __launch_bounds__(256) void k_scan1(const int* __restrict__ cnts,
                                                      int* __restrict__ bsum) {
  __shared__ int red[4];
  const int b = blockIdx.x, tid = threadIdx.x;
  const int start = b * SCAN_CHUNK + tid * 4;
  int s = 0;
#pragma unroll
  for (int i = 0; i < 4; ++i) {
    int idx = start + i;
    if (idx < NN) s += cnts[idx];
  }
#pragma unroll
  for (int o = 1; o < 64; o <<= 1) s += __shfl_xor(s, o);
  if ((tid & 63) == 0) red[tid >> 6] = s;
  __syncthreads();
  if (tid == 0) bsum[b] = red[0] + red[1] + red[2] + red[3];
}

static __global__ void k_scan2(const int* __restrict__ bsum, int* __restrict__ boff) {
  const int tid = threadIdx.x;  // 64 threads
  int orig = (tid < SCAN_NB) ? bsum[tid] : 0;
  int v = orig;
#pragma unroll
  for (int o = 1; o < 64; o <<= 1) {
    int u = __shfl_up(v, o);
    if (tid >= o) v += u;
  }
  if (tid < SCAN_NB) boff[tid] = v - orig;
}

static __global__ __launch_bounds__(256) void k_scan3(const int* __restrict__ cnts,
                                                      const int* __restrict__ boff,
                                                      int* __restrict__ base,
                                                      float* __restrict__ dinv) {
  __shared__ int wsum[4];
  const int b = blockIdx.x, tid = threadIdx.x;
  const int start = b * SCAN_CHUNK + tid * 4;
  int c[4];
  int s = 0;
#pragma unroll
  for (int i = 0; i < 4; ++i) {
    int idx = start + i;
    c[i] = (idx < NN) ? cnts[idx] : 0;
    s += c[i];
  }
  const int orig = s;
  const int lane = tid & 63, w = tid >> 6;
#pragma unroll
  for (int o = 1; o < 64; o <<= 1) {
    int u = __shfl_up(s, o);
    if (lane >= o) s += u;
  }
  if (lane == 63) wsum[w] = s;
  __syncthreads();
  int ex = s - orig + boff[b];
  for (int i = 0; i < w; ++i) ex += wsum[i];
#pragma unroll
  for (int i = 0; i < 4; ++i) {
    int idx = start + i;
    if (idx < NN) {
      base[idx] = ex;
      ex += c[i];
      dinv[idx] = rsqrtf((float)(c[i] + 1));  // +1 self-loop
    }
  }
  if (b == 0 && tid == 0) base[NN] = NE;
}

static __global__ void k_scatter(const int* __restrict__ row, const int* __restrict__ col,
                                 const int* __restrict__ base, int* __restrict__ cursor,
                                 int* __restrict__ colIdx) {
  int e = blockIdx.x * 256 + threadIdx.x;
  if (e >= NE) return;
  int r = row[e];
  int pos = base[r] + atomicAdd(&cursor[r], 1);
  colIdx[pos] = col[e];
}

// ---- weight split (layer 2 only): W2 -> Whi + Wlo (bf16 each) --------------

static __global__ void k_wsplit(const float* __restrict__ W2,
                                u16* __restrict__ whi, u16* __restrict__ wlo) {
  int i = blockIdx.x * 256 + threadIdx.x;
  if (i >= HID * HID) return;
  float w = W2[i];
  u16 hi = bf16rne(w);
  float fhi = __uint_as_float(((u32)hi) << 16);
  whi[i] = hi;
  wlo[i] = bf16rne(w - fhi);
}

// ---- layer-0 table: ew[t] = emb[t] @ W1^T + b1  (100 x 128, f32, 51 KB) ----

static __global__ __launch_bounds__(128) void k_ew(
    const float* __restrict__ emb, const float* __restrict__ W1,
    const float* __restrict__ b1, float* __restrict__ ew) {
  __shared__ float er[HID];
  const int t = blockIdx.x, o = threadIdx.x;
  er[o] = emb[(size_t)t * HID + o];
  __syncthreads();
  const float* wr = &W1[(size_t)o * HID];
  float acc = 0.f;
#pragma unroll
  for (int k = 0; k < HID; k += 4) {
    float4 w = *reinterpret_cast<const float4*>(&wr[k]);
    acc += er[k] * w.x + er[k + 1] * w.y + er[k + 2] * w.z + er[k + 3] * w.w;
  }
  ew[(size_t)t * HID + o] = acc + b1[o];
}

// ---- layer-0 fused GEMM+aggregate:
// x1[n] = relu( dinv[n] * ( dinv[n]*ew[H[n]] + sum_c dinv[c]*ew[H[c]] ) )
static __global__ void k_csr0(const int* __restrict__ base, const int* __restrict__ colIdx,
                              const int* __restrict__ H, const float* __restrict__ ew,
                              const float* __restrict__ dinv, u16* __restrict__ x) {
  int t = blockIdx.x * 256 + threadIdx.x;
  int node = t >> 5;
  if (node >= NN) return;
  const int lane = t & 31;
  const int j = lane * 4;  // f32 dims j..j+3

  const float dn = dinv[node];
  float4 wn = *reinterpret_cast<const float4*>(&ew[(size_t)H[node] * HID + j]);
  float a0 = dn * wn.x, a1 = dn * wn.y, a2 = dn * wn.z, a3 = dn * wn.w;

  const int s = base[node], e = base[node + 1];
  int i = s;
  for (; i + 2 <= e; i += 2) {
    int c0 = colIdx[i], c1 = colIdx[i + 1];
    float d0 = dinv[c0], d1 = dinv[c1];
    float4 w0 = *reinterpret_cast<const float4*>(&ew[(size_t)H[c0] * HID + j]);
    float4 w1 = *reinterpret_cast<const float4*>(&ew[(size_t)H[c1] * HID + j]);
    a0 += d0 * w0.x + d1 * w1.x;
    a1 += d0 * w0.y + d1 * w1.y;
    a2 += d0 * w0.z + d1 * w1.z;
    a3 += d0 * w0.w + d1 * w1.w;
  }
  if (i < e) {
    int c0 = colIdx[i];
    float d0 = dinv[c0];
    float4 w0 = *reinterpret_cast<const float4*>(&ew[(size_t)H[c0] * HID + j]);
    a0 += d0 * w0.x; a1 += d0 * w0.y; a2 += d0 * w0.z; a3 += d0 * w0.w;
  }
  a0 = fmaxf(a0 * dn, 0.f);
  a1 = fmaxf(a1 * dn, 0.f);
  a2 = fmaxf(a2 * dn, 0.f);
  a3 = fmaxf(a3 * dn, 0.f);
  *reinterpret_cast<uint2*>((u32*)x + (size_t)node * 64 + lane * 2) =
      make_uint2(pack2bf(a0, a1), pack2bf(a2, a3));
}

// ---- MFMA GEMM (layer 2): g(bf16) = (x @ W2^T + b2) * dinv[row] ------------
// A = W-tile (features, wave-resident), B = x-tile (nodes, streamed).
// All TPB tiles' x-loads issued up front (16 VMEM in flight), then MFMAs.
// Node range padded to NN_P: no guards; pad rows produce garbage never read.

static __global__ __launch_bounds__(256) void k_gemm(
    const u16* __restrict__ x,
    const u16* __restrict__ whi, const u16* __restrict__ wlo,
    const float* __restrict__ bias, const float* __restrict__ dinv,
    u16* __restrict__ g) {
  const int tid = threadIdx.x;
  const int wv = tid >> 6;        // wave 0..3 -> feature-tiles 2wv, 2wv+1
  const int l = tid & 63;
  const int l16 = l & 15, g4 = l >> 4;

  s16x8 wh[2][4], wl[2][4];
  float4 bb[2];
#pragma unroll
  for (int tt = 0; tt < 2; ++tt) {
    const int trow = (wv * 2 + tt) * 16 + l16;
#pragma unroll
    for (int s = 0; s < 4; ++s) {
      const int koff = s * 32 + g4 * 8;
      wh[tt][s] = *reinterpret_cast<const s16x8*>(&whi[(size_t)trow * HID + koff]);
      wl[tt][s] = *reinterpret_cast<const s16x8*>(&wlo[(size_t)trow * HID + koff]);
    }
    bb[tt] = *reinterpret_cast<const float4*>(&bias[(wv * 2 + tt) * 16 + g4 * 4]);
  }

  const int n0 = blockIdx.x * (TPB * 16) + l16;

  // issue ALL x-loads + dinv loads up front
  s16x8 xf[TPB][4];
  float dvv[TPB];
#pragma unroll
  for (int it = 0; it < TPB; ++it) {
    const int n = n0 + it * 16;
#pragma unroll
    for (int s = 0; s < 4; ++s)
      xf[it][s] = *reinterpret_cast<const s16x8*>(&x[(size_t)n * HID + s * 32 + g4 * 8]);
    dvv[it] = dinv[n];
  }

  f32x4 acc[TPB][2];
#pragma unroll
  for (int it = 0; it < TPB; ++it) {
    acc[it][0] = (f32x4){0.f, 0.f, 0.f, 0.f};
    acc[it][1] = (f32x4){0.f, 0.f, 0.f, 0.f};
  }
#pragma unroll
  for (int it = 0; it < TPB; ++it) {
#pragma unroll
    for (int s = 0; s < 4; ++s) {
#pragma unroll
      for (int tt = 0; tt < 2; ++tt) {
        acc[it][tt] = __builtin_amdgcn_mfma_f32_16x16x32_bf16(wh[tt][s], xf[it][s], acc[it][tt], 0, 0, 0);
        acc[it][tt] = __builtin_amdgcn_mfma_f32_16x16x32_bf16(wl[tt][s], xf[it][s], acc[it][tt], 0, 0, 0);
      }
    }
  }

#pragma unroll
  for (int it = 0; it < TPB; ++it) {
    const int n = n0 + it * 16;
#pragma unroll
    for (int tt = 0; tt < 2; ++tt) {
      const float v0 = (acc[it][tt][0] + bb[tt].x) * dvv[it];
      const float v1 = (acc[it][tt][1] + bb[tt].y) * dvv[it];
      const float v2 = (acc[it][tt][2] + bb[tt].z) * dvv[it];
      const float v3 = (acc[it][tt][3] + bb[tt].w) * dvv[it];
      *reinterpret_cast<uint2*>(&g[(size_t)n * HID + (wv * 2 + tt) * 16 + g4 * 4]) =
          make_uint2(pack2bf(v0, v1), pack2bf(v2, v3));
    }
  }
}

// ---- fused layer-1 aggregate + relu + mean-pool (batch SORTED) -------------
// 64 nodes/block, 4 lanes/node (32 dims each). Stage relu'd rows in LDS,
// then segmented per-dim reduction -> few f32 atomics per block.

static __global__ __launch_bounds__(256) void k_csr_pool(
    const int* __restrict__ base, const int* __restrict__ colIdx,
    const u16* __restrict__ g, const float* __restrict__ dinv,
    const int* __restrict__ batch, float* __restrict__ poolSum) {
  __shared__ float xl[64][HID];  // 32 KB
  __shared__ int bl[64];
  const int tid = threadIdx.x;
  const int nl = tid >> 2;       // local node 0..63
  const int j = tid & 3;         // quarter: dims j*32..j*32+31
  const int node = blockIdx.x * 64 + nl;
  const u32* gw = (const u32*)g;

  float a[32];
  if (node < NN) {
    const u32* self = gw + (size_t)node * 64 + j * 16;
#pragma unroll
    for (int q = 0; q < 4; ++q) {
      uint4 v = *reinterpret_cast<const uint4*>(self + q * 4);
      a[q * 8 + 0] = bflo(v.x); a[q * 8 + 1] = bfhi(v.x);
      a[q * 8 + 2] = bflo(v.y); a[q * 8 + 3] = bfhi(v.y);
      a[q * 8 + 4] = bflo(v.z); a[q * 8 + 5] = bfhi(v.z);
      a[q * 8 + 6] = bflo(v.w); a[q * 8 + 7] = bfhi(v.w);
    }
    const int s = base[node], e = base[node + 1];
    int i = s;
    for (; i + 2 <= e; i += 2) {
      const u32* r0 = gw + (size_t)colIdx[i] * 64 + j * 16;
      const u32* r1 = gw + (size_t)colIdx[i + 1] * 64 + j * 16;
      uint4 v0[4], v1[4];
#pragma unroll
      for (int q = 0; q < 4; ++q) v0[q] = *reinterpret_cast<const uint4*>(r0 + q * 4);
#pragma unroll
      for (int q = 0; q < 4; ++q) v1[q] = *reinterpret_cast<const uint4*>(r1 + q * 4);
#pragma unroll
      for (int q = 0; q < 4; ++q) {
        a[q * 8 + 0] += bflo(v0[q].x) + bflo(v1[q].x);
        a[q * 8 + 1] += bfhi(v0[q].x) + bfhi(v1[q].x);
        a[q * 8 + 2] += bflo(v0[q].y) + bflo(v1[q].y);
        a[q * 8 + 3] += bfhi(v0[q].y) + bfhi(v1[q].y);
        a[q * 8 + 4] += bflo(v0[q].z) + bflo(v1[q].z);
        a[q * 8 + 5] += bfhi(v0[q].z) + bfhi(v1[q].z);
        a[q * 8 + 6] += bflo(v0[q].w) + bflo(v1[q].w);
        a[q * 8 + 7] += bfhi(v0[q].w) + bfhi(v1[q].w);
      }
    }
    if (i < e) {
      const u32* r0 = gw + (size_t)colIdx[i] * 64 + j * 16;
#pragma unroll
      for (int q = 0; q < 4; ++q) {
        uint4 v = *reinterpret_cast<const uint4*>(r0 + q * 4);
        a[q * 8 + 0] += bflo(v.x); a[q * 8 + 1] += bfhi(v.x);
        a[q * 8 + 2] += bflo(v.y); a[q * 8 + 3] += bfhi(v.y);
        a[q * 8 + 4] += bflo(v.z); a[q * 8 + 5] += bfhi(v.z);
        a[q * 8 + 6] += bflo(v.w); a[q * 8 + 7] += bfhi(v.w);
      }
    }
    const float d = dinv[node];
#pragma unroll
    for (int k = 0; k < 32; ++k) a[k] = fmaxf(a[k] * d, 0.f);
  } else {
#pragma unroll
    for (int k = 0; k < 32; ++k) a[k] = 0.f;
  }
#pragma unroll
  for (int k = 0; k < 32; ++k) xl[nl][j * 32 + k] = a[k];
  if (tid < 64) {
    int n2 = blockIdx.x * 64 + tid;
    bl[tid] = batch[n2 < NN ? n2 : NN - 1];
  }
  __syncthreads();

  // segmented reduction: thread (d, half) walks 32 nodes, flush on graph change
  const int d = tid & 127;
  const int half = tid >> 7;
  int gcur = bl[half * 32];
  float run = 0.f;
#pragma unroll 8
  for (int nd = half * 32; nd < half * 32 + 32; ++nd) {
    int gb = bl[nd];
    if (gb != gcur) {
      atomicAdd(&poolSum[gcur * HID + d], run);
      run = 0.f; gcur = gb;
    }
    run += xl[nd][d];
  }
  atomicAdd(&poolSum[gcur * HID + d], run);
}

// ---- head: out[g] = (poolSum[g]/cnt[g]) @ Wout^T + bout --------------------

static __device__ __forceinline__ int lb(const int* __restrict__ b, int n, int v) {
  int lo = 0, hi = n;
  while (lo < hi) { int m = (lo + hi) >> 1; if (b[m] < v) lo = m + 1; else hi = m; }
  return lo;
}

static __global__ __launch_bounds__(64) void k_head(
    const int* __restrict__ batch, const float* __restrict__ poolSum,
    const float* __restrict__ Wout, const float* __restrict__ bout,
    float* __restrict__ out) {
  const int g = blockIdx.x, o = threadIdx.x;
  const int s = lb(batch, NN, g);
  const int e = lb(batch, NN, g + 1);
  const float inv = 1.0f / fmaxf((float)(e - s), 1.0f);
  const float* ps = &poolSum[(size_t)g * HID];
  const float* wr = &Wout[(size_t)o * HID];
  float acc = 0.f;
#pragma unroll
  for (int k = 0; k < HID; k += 4) {
    float4 p = *reinterpret_cast<const float4*>(&ps[k]);
    float4 w = *reinterpret_cast<const float4*>(&wr[k]);
    acc += p.x * w.x + p.y * w.y + p.z * w.z + p.w * w.w;
  }
  out[g * NOUT_ + o] = acc * inv + bout[o];
}

extern "C" void kernel_launch(void* const* d_in, const int* in_sizes, int n_in,
                              void* d_out, int out_size, void* d_ws, size_t ws_size,
                              hipStream_t stream) {
  const int* H     = (const int*)d_in[0];
  const int* ei    = (const int*)d_in[1];
  const int* row   = ei;
  const int* col   = ei + NE;
  const int* batch = (const int*)d_in[2];
  const float* emb  = (const float*)d_in[3];
  const float* W1   = (const float*)d_in[4];
  const float* b1   = (const float*)d_in[5];
  const float* W2   = (const float*)d_in[6];
  const float* b2   = (const float*)d_in[7];
  const float* Wout = (const float*)d_in[8];
  const float* bout = (const float*)d_in[9];

  char* ws = (char*)d_ws;
  size_t off = 0;
  auto alloc = [&](size_t bytes) -> void* {
    void* p = (void*)(ws + off);
    off += (bytes + 255) & ~(size_t)255;
    return p;
  };
  int*   cnts    = (int*)alloc((size_t)NN * 4);
  int*   cursor  = (int*)alloc((size_t)NN * 4);
  int*   base    = (int*)alloc((size_t)(NN + 1) * 4);
  int*   bsum    = (int*)alloc((size_t)SCAN_NB * 4);
  int*   boff    = (int*)alloc((size_t)SCAN_NB * 4);
  int*   colIdx  = (int*)alloc((size_t)NE * 4);
  float* dinv    = (float*)alloc((size_t)NN_P * 4);   // padded (pad garbage ok)
  float* ew      = (float*)alloc((size_t)NT * HID * 4);
  u16*   whi     = (u16*)alloc((size_t)HID * HID * 2);
  u16*   wlo     = (u16*)alloc((size_t)HID * HID * 2);
  u16*   xbuf    = (u16*)alloc((size_t)NN_P * HID * 2);  // padded
  u16*   gbuf    = (u16*)alloc((size_t)NN_P * HID * 2);  // padded
  float* poolSum = (float*)alloc((size_t)NG * HID * 4);
  (void)ws_size; (void)in_sizes; (void)n_in; (void)out_size;

  const int nbE   = (NE + 255) / 256;
  const int nbN32 = (NN * 32 + 255) / 256;

  // CSR build + dinv + layer-0 table + W2 split + poolSum zero
  k_zero<<<(NN / 4 + 255) / 256, 256, 0, stream>>>(cnts, cursor);
  hipMemsetAsync(poolSum, 0, (size_t)NG * HID * 4, stream);
  k_wsplit<<<(HID * HID + 255) / 256, 256, 0, stream>>>(W2, whi, wlo);
  k_ew<<<NT, 128, 0, stream>>>(emb, W1, b1, ew);
  k_count<<<nbE, 256, 0, stream>>>(row, cnts);
  k_scan1<<<SCAN_NB, 256, 0, stream>>>(cnts, bsum);
  k_scan2<<<1, 64, 0, stream>>>(bsum, boff);
  k_scan3<<<SCAN_NB, 256, 0, stream>>>(cnts, boff, base, dinv);
  k_scatter<<<nbE, 256, 0, stream>>>(row, col, base, cursor, colIdx);

  // layer 0: fully fused (table gather + aggregate + relu)
  k_csr0<<<nbN32, 256, 0, stream>>>(base, colIdx, H, ew, dinv, xbuf);
  // layer 1: MFMA GEMM, then fused aggregate+relu+pool
  k_gemm<<<GEMM_GRID, 256, 0, stream>>>(xbuf, whi, wlo, b2, dinv, gbuf);
  k_csr_pool<<<NN_P / 64, 256, 0, stream>>>(base, colIdx, gbuf, dinv, batch, poolSum);

  k_head<<<NG, NOUT_, 0, stream>>>(batch, poolSum, Wout, bout, (float*)d_out);
}

// Round 11
// 167.023 us; speedup vs baseline: 1.4852x; 1.0326x over previous
//
#include <hip/hip_runtime.h>

#define NN   50000
#define NE   600000
#define HID  128
#define NOUT_ 64
#define NG   256
#define NT   100   // NUM_TYPES

#define NN_P   50048                 // padded to 3128 full 16-node tiles
#define NTILES (NN_P / 16)           // 3128
#define TPB    4                     // node-tiles per block
#define GEMM_GRID (NTILES / TPB)     // 782

#define SCAN_CHUNK 1024
#define SCAN_NB ((NN + SCAN_CHUNK - 1) / SCAN_CHUNK)  // 49

typedef unsigned int u32;
typedef unsigned short u16;
typedef __attribute__((ext_vector_type(8))) short s16x8;  // 8 bf16 (4 VGPRs)
typedef __attribute__((ext_vector_type(4))) float f32x4;

// bf16 helpers (bit ops; accumulate in f32, store RNE bf16)
static __device__ __forceinline__ float bflo(u32 u) { return __uint_as_float(u << 16); }
static __device__ __forceinline__ float bfhi(u32 u) { return __uint_as_float(u & 0xffff0000u); }
static __device__ __forceinline__ u32 pack2bf(float lo, float hi) {
  u32 ul = __float_as_uint(lo), uh = __float_as_uint(hi);
  ul = (ul + 0x7fffu + ((ul >> 16) & 1u)) >> 16;
  uh = (uh + 0x7fffu + ((uh >> 16) & 1u)) >> 16;
  return ul | (uh << 16);
}
static __device__ __forceinline__ u16 bf16rne(float f) {
  u32 u = __float_as_uint(f);
  u = (u + 0x7fffu + ((u >> 16) & 1u)) >> 16;
  return (u16)u;
}

// ---- fused setup: zero cnts/cursor/poolSum + W2 split + ew table -----------
// role-split by blockIdx (no memsetAsync: ROCm small-fill = 1-WG kernel, ~43us)

#define NB_Z 49                    // zero cnts+cursor (1024 ints each / block)
#define NB_P 32                    // zero poolSum (32768 floats, 1024/block)
#define NB_W 64                    // W2 split (16384 elems)
#define NB_E 50                    // ew table (2 types / block)
#define SETUP_GRID (NB_Z + NB_P + NB_W + NB_E)  // 195

static __global__ __launch_bounds__(256) void k_setup(
    int* __restrict__ cnts, int* __restrict__ cursor, float* __restrict__ poolSum,
    const float* __restrict__ W2, u16* __restrict__ whi, u16* __restrict__ wlo,
    const float* __restrict__ emb, const float* __restrict__ W1,
    const float* __restrict__ b1, float* __restrict__ ew) {
  __shared__ float er[2][HID];
  const int b = blockIdx.x, tid = threadIdx.x;
  if (b < NB_Z) {
    int i = b * 1024 + tid * 4;
    if (i < NN) {  // NN % 4 == 0
      *reinterpret_cast<int4*>(&cnts[i]) = make_int4(0, 0, 0, 0);
      *reinterpret_cast<int4*>(&cursor[i]) = make_int4(0, 0, 0, 0);
    }
  } else if (b < NB_Z + NB_P) {
    int i = (b - NB_Z) * 1024 + tid * 4;  // < 32768 exactly
    *reinterpret_cast<float4*>(&poolSum[i]) = make_float4(0.f, 0.f, 0.f, 0.f);
  } else if (b < NB_Z + NB_P + NB_W) {
    int i = (b - NB_Z - NB_P) * 256 + tid;  // < 16384 exactly
    float w = W2[i];
    u16 hi = bf16rne(w);
    whi[i] = hi;
    wlo[i] = bf16rne(w - __uint_as_float(((u32)hi) << 16));
  } else {
    const int half = tid >> 7, o = tid & 127;
    const int t = (b - NB_Z - NB_P - NB_W) * 2 + half;  // < 100 exactly
    er[half][o] = emb[(size_t)t * HID + o];
    __syncthreads();
    const float* wr = &W1[(size_t)o * HID];
    const float* e0 = er[half];
    float acc = 0.f;
#pragma unroll
    for (int k = 0; k < HID; k += 4) {
      float4 w = *reinterpret_cast<const float4*>(&wr[k]);
      acc += e0[k] * w.x + e0[k + 1] * w.y + e0[k + 2] * w.z + e0[k + 3] * w.w;
    }
    ew[(size_t)t * HID + o] = acc + b1[o];
  }
}

// ---- CSR build -------------------------------------------------------------

static __global__ void k_count(const int* __restrict__ row, int* __restrict__ cnts) {
  int e = blockIdx.x * 256 + threadIdx.x;
  if (e < NE) atomicAdd(&cnts[row[e]], 1);
}

static __global__ __launch_bounds__(256) void k_scan1(const int* __restrict__ cnts,
                                                      int* __restrict__ bsum) {
  __shared__ int red[4];
  const int b = blockIdx.x, tid = threadIdx.x;
  const int start = b * SCAN_CHUNK + tid * 4;
  int s = 0;
#pragma unroll
  for (int i = 0; i < 4; ++i) {
    int idx = start + i;
    if (idx < NN) s += cnts[idx];
  }
#pragma unroll
  for (int o = 1; o < 64; o <<= 1) s += __shfl_xor(s, o);
  if ((tid & 63) == 0) red[tid >> 6] = s;
  __syncthreads();
  if (tid == 0) bsum[b] = red[0] + red[1] + red[2] + red[3];
}

static __global__ void k_scan2(const int* __restrict__ bsum, int* __restrict__ boff) {
  const int tid = threadIdx.x;  // 64 threads
  int orig = (tid < SCAN_NB) ? bsum[tid] : 0;
  int v = orig;
#pragma unroll
  for (int o = 1; o < 64; o <<= 1) {
    int u = __shfl_up(v, o);
    if (tid >= o) v += u;
  }
  if (tid < SCAN_NB) boff[tid] = v - orig;
}

// local exclusive scan + block offset -> base; emits dinv and packed hd=(H,dinv)
static __global__ __launch_bounds__(256) void k_scan3(const int* __restrict__ cnts,
                                                      const int* __restrict__ boff,
                                                      const int* __restrict__ H,
                                                      int* __restrict__ base,
                                                      float* __restrict__ dinv,
                                                      int2* __restrict__ hd) {
  __shared__ int wsum[4];
  const int b = blockIdx.x, tid = threadIdx.x;
  const int start = b * SCAN_CHUNK + tid * 4;
  int c[4];
  int s = 0;
#pragma unroll
  for (int i = 0; i < 4; ++i) {
    int idx = start + i;
    c[i] = (idx < NN) ? cnts[idx] : 0;
    s += c[i];
  }
  const int orig = s;
  const int lane = tid & 63, w = tid >> 6;
#pragma unroll
  for (int o = 1; o < 64; o <<= 1) {
    int u = __shfl_up(s, o);
    if (lane >= o) s += u;
  }
  if (lane == 63) wsum[w] = s;
  __syncthreads();
  int ex = s - orig + boff[b];
  for (int i = 0; i < w; ++i) ex += wsum[i];
#pragma unroll
  for (int i = 0; i < 4; ++i) {
    int idx = start + i;
    if (idx < NN) {
      base[idx] = ex;
      ex += c[i];
      float dv = rsqrtf((float)(c[i] + 1));  // +1 self-loop
      dinv[idx] = dv;
      hd[idx] = make_int2(H[idx], __float_as_int(dv));
    }
  }
  if (b == 0 && tid == 0) base[NN] = NE;
}

static __global__ void k_scatter(const int* __restrict__ row, const int* __restrict__ col,
                                 const int* __restrict__ base, int* __restrict__ cursor,
                                 int* __restrict__ colIdx) {
  int e = blockIdx.x * 256 + threadIdx.x;
  if (e >= NE) return;
  int r = row[e];
  int pos = base[r] + atomicAdd(&cursor[r], 1);
  colIdx[pos] = col[e];
}

// ---- layer-0 fused GEMM+aggregate:
// x1[n] = relu( dinv[n] * ( dinv[n]*ew[H[n]] + sum_c dinv[c]*ew[H[c]] ) )
static __global__ void k_csr0(const int* __restrict__ base, const int* __restrict__ colIdx,
                              const int2* __restrict__ hd, const float* __restrict__ ew,
                              u16* __restrict__ x) {
  int t = blockIdx.x * 256 + threadIdx.x;
  int node = t >> 5;
  if (node >= NN) return;
  const int lane = t & 31;
  const int j = lane * 4;  // f32 dims j..j+3

  const int2 hn = hd[node];
  const float dn = __int_as_float(hn.y);
  float4 wn = *reinterpret_cast<const float4*>(&ew[(size_t)hn.x * HID + j]);
  float a0 = dn * wn.x, a1 = dn * wn.y, a2 = dn * wn.z, a3 = dn * wn.w;

  const int s = base[node], e = base[node + 1];
  int i = s;
  for (; i + 4 <= e; i += 4) {
    int2 h0 = hd[colIdx[i]], h1 = hd[colIdx[i + 1]];
    int2 h2 = hd[colIdx[i + 2]], h3 = hd[colIdx[i + 3]];
    float4 w0 = *reinterpret_cast<const float4*>(&ew[(size_t)h0.x * HID + j]);
    float4 w1 = *reinterpret_cast<const float4*>(&ew[(size_t)h1.x * HID + j]);
    float4 w2 = *reinterpret_cast<const float4*>(&ew[(size_t)h2.x * HID + j]);
    float4 w3 = *reinterpret_cast<const float4*>(&ew[(size_t)h3.x * HID + j]);
    float d0 = __int_as_float(h0.y), d1 = __int_as_float(h1.y);
    float d2 = __int_as_float(h2.y), d3 = __int_as_float(h3.y);
    a0 += d0 * w0.x + d1 * w1.x + d2 * w2.x + d3 * w3.x;
    a1 += d0 * w0.y + d1 * w1.y + d2 * w2.y + d3 * w3.y;
    a2 += d0 * w0.z + d1 * w1.z + d2 * w2.z + d3 * w3.z;
    a3 += d0 * w0.w + d1 * w1.w + d2 * w2.w + d3 * w3.w;
  }
  for (; i < e; ++i) {
    int2 h0 = hd[colIdx[i]];
    float d0 = __int_as_float(h0.y);
    float4 w0 = *reinterpret_cast<const float4*>(&ew[(size_t)h0.x * HID + j]);
    a0 += d0 * w0.x; a1 += d0 * w0.y; a2 += d0 * w0.z; a3 += d0 * w0.w;
  }
  a0 = fmaxf(a0 * dn, 0.f);
  a1 = fmaxf(a1 * dn, 0.f);
  a2 = fmaxf(a2 * dn, 0.f);
  a3 = fmaxf(a3 * dn, 0.f);
  *reinterpret_cast<uint2*>((u32*)x + (size_t)node * 64 + lane * 2) =
      make_uint2(pack2bf(a0, a1), pack2bf(a2, a3));
}

// ---- MFMA GEMM (layer 2): g(bf16) = (x @ W2^T + b2) * dinv[row] ------------
// A = W-tile (features, wave-resident), B = x-tile (nodes, streamed).
// All TPB tiles' x-loads issued up front; node range padded to NN_P.

static __global__ __launch_bounds__(256) void k_gemm(
    const u16* __restrict__ x,
    const u16* __restrict__ whi, const u16* __restrict__ wlo,
    const float* __restrict__ bias, const float* __restrict__ dinv,
    u16* __restrict__ g) {
  const int tid = threadIdx.x;
  const int wv = tid >> 6;        // wave 0..3 -> feature-tiles 2wv, 2wv+1
  const int l = tid & 63;
  const int l16 = l & 15, g4 = l >> 4;

  s16x8 wh[2][4], wl[2][4];
  float4 bb[2];
#pragma unroll
  for (int tt = 0; tt < 2; ++tt) {
    const int trow = (wv * 2 + tt) * 16 + l16;
#pragma unroll
    for (int s = 0; s < 4; ++s) {
      const int koff = s * 32 + g4 * 8;
      wh[tt][s] = *reinterpret_cast<const s16x8*>(&whi[(size_t)trow * HID + koff]);
      wl[tt][s] = *reinterpret_cast<const s16x8*>(&wlo[(size_t)trow * HID + koff]);
    }
    bb[tt] = *reinterpret_cast<const float4*>(&bias[(wv * 2 + tt) * 16 + g4 * 4]);
  }

  const int n0 = blockIdx.x * (TPB * 16) + l16;

  s16x8 xf[TPB][4];
  float dvv[TPB];
#pragma unroll
  for (int it = 0; it < TPB; ++it) {
    const int n = n0 + it * 16;
#pragma unroll
    for (int s = 0; s < 4; ++s)
      xf[it][s] = *reinterpret_cast<const s16x8*>(&x[(size_t)n * HID + s * 32 + g4 * 8]);
    dvv[it] = dinv[n];
  }

  f32x4 acc[TPB][2];
#pragma unroll
  for (int it = 0; it < TPB; ++it) {
    acc[it][0] = (f32x4){0.f, 0.f, 0.f, 0.f};
    acc[it][1] = (f32x4){0.f, 0.f, 0.f, 0.f};
  }
#pragma unroll
  for (int it = 0; it < TPB; ++it) {
#pragma unroll
    for (int s = 0; s < 4; ++s) {
#pragma unroll
      for (int tt = 0; tt < 2; ++tt) {
        acc[it][tt] = __builtin_amdgcn_mfma_f32_16x16x32_bf16(wh[tt][s], xf[it][s], acc[it][tt], 0, 0, 0);
        acc[it][tt] = __builtin_amdgcn_mfma_f32_16x16x32_bf16(wl[tt][s], xf[it][s], acc[it][tt], 0, 0, 0);
      }
    }
  }

#pragma unroll
  for (int it = 0; it < TPB; ++it) {
    const int n = n0 + it * 16;
#pragma unroll
    for (int tt = 0; tt < 2; ++tt) {
      const float v0 = (acc[it][tt][0] + bb[tt].x) * dvv[it];
      const float v1 = (acc[it][tt][1] + bb[tt].y) * dvv[it];
      const float v2 = (acc[it][tt][2] + bb[tt].z) * dvv[it];
      const float v3 = (acc[it][tt][3] + bb[tt].w) * dvv[it];
      *reinterpret_cast<uint2*>(&g[(size_t)n * HID + (wv * 2 + tt) * 16 + g4 * 4]) =
          make_uint2(pack2bf(v0, v1), pack2bf(v2, v3));
    }
  }
}

// ---- fused layer-1 aggregate + relu + mean-pool (batch SORTED) -------------

static __global__ __launch_bounds__(256) void k_csr_pool(
    const int* __restrict__ base, const int* __restrict__ colIdx,
    const u16* __restrict__ g, const float* __restrict__ dinv,
    const int* __restrict__ batch, float* __restrict__ poolSum) {
  __shared__ float xl[64][HID];  // 32 KB
  __shared__ int bl[64];
  const int tid = threadIdx.x;
  const int nl = tid >> 2;       // local node 0..63
  const int j = tid & 3;         // quarter: dims j*32..j*32+31
  const int node = blockIdx.x * 64 + nl;
  const u32* gw = (const u32*)g;

  float a[32];
  if (node < NN) {
    const u32* self = gw + (size_t)node * 64 + j * 16;
#pragma unroll
    for (int q = 0; q < 4; ++q) {
      uint4 v = *reinterpret_cast<const uint4*>(self + q * 4);
      a[q * 8 + 0] = bflo(v.x); a[q * 8 + 1] = bfhi(v.x);
      a[q * 8 + 2] = bflo(v.y); a[q * 8 + 3] = bfhi(v.y);
      a[q * 8 + 4] = bflo(v.z); a[q * 8 + 5] = bfhi(v.z);
      a[q * 8 + 6] = bflo(v.w); a[q * 8 + 7] = bfhi(v.w);
    }
    const int s = base[node], e = base[node + 1];
    int i = s;
    for (; i + 2 <= e; i += 2) {
      const u32* r0 = gw + (size_t)colIdx[i] * 64 + j * 16;
      const u32* r1 = gw + (size_t)colIdx[i + 1] * 64 + j * 16;
      uint4 v0[4], v1[4];
#pragma unroll
      for (int q = 0; q < 4; ++q) v0[q] = *reinterpret_cast<const uint4*>(r0 + q * 4);
#pragma unroll
      for (int q = 0; q < 4; ++q) v1[q] = *reinterpret_cast<const uint4*>(r1 + q * 4);
#pragma unroll
      for (int q = 0; q < 4; ++q) {
        a[q * 8 + 0] += bflo(v0[q].x) + bflo(v1[q].x);
        a[q * 8 + 1] += bfhi(v0[q].x) + bfhi(v1[q].x);
        a[q * 8 + 2] += bflo(v0[q].y) + bflo(v1[q].y);
        a[q * 8 + 3] += bfhi(v0[q].y) + bfhi(v1[q].y);
        a[q * 8 + 4] += bflo(v0[q].z) + bflo(v1[q].z);
        a[q * 8 + 5] += bfhi(v0[q].z) + bfhi(v1[q].z);
        a[q * 8 + 6] += bflo(v0[q].w) + bflo(v1[q].w);
        a[q * 8 + 7] += bfhi(v0[q].w) + bfhi(v1[q].w);
      }
    }
    if (i < e) {
      const u32* r0 = gw + (size_t)colIdx[i] * 64 + j * 16;
#pragma unroll
      for (int q = 0; q < 4; ++q) {
        uint4 v = *reinterpret_cast<const uint4*>(r0 + q * 4);
        a[q * 8 + 0] += bflo(v.x); a[q * 8 + 1] += bfhi(v.x);
        a[q * 8 + 2] += bflo(v.y); a[q * 8 + 3] += bfhi(v.y);
        a[q * 8 + 4] += bflo(v.z); a[q * 8 + 5] += bfhi(v.z);
        a[q * 8 + 6] += bflo(v.w); a[q * 8 + 7] += bfhi(v.w);
      }
    }
    const float d = dinv[node];
#pragma unroll
    for (int k = 0; k < 32; ++k) a[k] = fmaxf(a[k] * d, 0.f);
  } else {
#pragma unroll
    for (int k = 0; k < 32; ++k) a[k] = 0.f;
  }
#pragma unroll
  for (int k = 0; k < 32; ++k) xl[nl][j * 32 + k] = a[k];
  if (tid < 64) {
    int n2 = blockIdx.x * 64 + tid;
    bl[tid] = batch[n2 < NN ? n2 : NN - 1];
  }
  __syncthreads();

  // segmented reduction: thread (d, half) walks 32 nodes, flush on graph change
  const int d = tid & 127;
  const int half = tid >> 7;
  int gcur = bl[half * 32];
  float run = 0.f;
#pragma unroll 8
  for (int nd = half * 32; nd < half * 32 + 32; ++nd) {
    int gb = bl[nd];
    if (gb != gcur) {
      atomicAdd(&poolSum[gcur * HID + d], run);
      run = 0.f; gcur = gb;
    }
    run += xl[nd][d];
  }
  atomicAdd(&poolSum[gcur * HID + d], run);
}

// ---- head: out[g] = (poolSum[g]/cnt[g]) @ Wout^T + bout --------------------

static __device__ __forceinline__ int lb(const int* __restrict__ b, int n, int v) {
  int lo = 0, hi = n;
  while (lo < hi) { int m = (lo + hi) >> 1; if (b[m] < v) lo = m + 1; else hi = m; }
  return lo;
}

static __global__ __launch_bounds__(64) void k_head(
    const int* __restrict__ batch, const float* __restrict__ poolSum,
    const float* __restrict__ Wout, const float* __restrict__ bout,
    float* __restrict__ out) {
  const int g = blockIdx.x, o = threadIdx.x;
  const int s = lb(batch, NN, g);
  const int e = lb(batch, NN, g + 1);
  const float inv = 1.0f / fmaxf((float)(e - s), 1.0f);
  const float* ps = &poolSum[(size_t)g * HID];
  const float* wr = &Wout[(size_t)o * HID];
  float acc = 0.f;
#pragma unroll
  for (int k = 0; k < HID; k += 4) {
    float4 p = *reinterpret_cast<const float4*>(&ps[k]);
    float4 w = *reinterpret_cast<const float4*>(&wr[k]);
    acc += p.x * w.x + p.y * w.y + p.z * w.z + p.w * w.w;
  }
  out[g * NOUT_ + o] = acc * inv + bout[o];
}

extern "C" void kernel_launch(void* const* d_in, const int* in_sizes, int n_in,
                              void* d_out, int out_size, void* d_ws, size_t ws_size,
                              hipStream_t stream) {
  const int* H     = (const int*)d_in[0];
  const int* ei    = (const int*)d_in[1];
  const int* row   = ei;
  const int* col   = ei + NE;
  const int* batch = (const int*)d_in[2];
  const float* emb  = (const float*)d_in[3];
  const float* W1   = (const float*)d_in[4];
  const float* b1   = (const float*)d_in[5];
  const float* W2   = (const float*)d_in[6];
  const float* b2   = (const float*)d_in[7];
  const float* Wout = (const float*)d_in[8];
  const float* bout = (const float*)d_in[9];

  char* ws = (char*)d_ws;
  size_t off = 0;
  auto alloc = [&](size_t bytes) -> void* {
    void* p = (void*)(ws + off);
    off += (bytes + 255) & ~(size_t)255;
    return p;
  };
  int*   cnts    = (int*)alloc((size_t)NN * 4);
  int*   cursor  = (int*)alloc((size_t)NN * 4);
  int*   base    = (int*)alloc((size_t)(NN + 1) * 4);
  int*   bsum    = (int*)alloc((size_t)SCAN_NB * 4);
  int*   boff    = (int*)alloc((size_t)SCAN_NB * 4);
  int*   colIdx  = (int*)alloc((size_t)NE * 4);
  float* dinv    = (float*)alloc((size_t)NN_P * 4);   // padded (pad garbage ok)
  int2*  hd      = (int2*)alloc((size_t)NN * 8);
  float* ew      = (float*)alloc((size_t)NT * HID * 4);
  u16*   whi     = (u16*)alloc((size_t)HID * HID * 2);
  u16*   wlo     = (u16*)alloc((size_t)HID * HID * 2);
  u16*   xbuf    = (u16*)alloc((size_t)NN_P * HID * 2);  // padded
  u16*   gbuf    = (u16*)alloc((size_t)NN_P * HID * 2);  // padded
  float* poolSum = (float*)alloc((size_t)NG * HID * 4);
  (void)ws_size; (void)in_sizes; (void)n_in; (void)out_size;

  const int nbE   = (NE + 255) / 256;
  const int nbN32 = (NN * 32 + 255) / 256;

  // setup (zero + wsplit + ew) then CSR build
  k_setup<<<SETUP_GRID, 256, 0, stream>>>(cnts, cursor, poolSum,
                                          W2, whi, wlo, emb, W1, b1, ew);
  k_count<<<nbE, 256, 0, stream>>>(row, cnts);
  k_scan1<<<SCAN_NB, 256, 0, stream>>>(cnts, bsum);
  k_scan2<<<1, 64, 0, stream>>>(bsum, boff);
  k_scan3<<<SCAN_NB, 256, 0, stream>>>(cnts, boff, H, base, dinv, hd);
  k_scatter<<<nbE, 256, 0, stream>>>(row, col, base, cursor, colIdx);

  // layer 0: fully fused (table gather + aggregate + relu)
  k_csr0<<<nbN32, 256, 0, stream>>>(base, colIdx, hd, ew, xbuf);
  // layer 1: MFMA GEMM, then fused aggregate+relu+pool
  k_gemm<<<GEMM_GRID, 256, 0, stream>>>(xbuf, whi, wlo, b2, dinv, gbuf);
  k_csr_pool<<<NN_P / 64, 256, 0, stream>>>(base, colIdx, gbuf, dinv, batch, poolSum);

  k_head<<<NG, NOUT_, 0, stream>>>(batch, poolSum, Wout, bout, (float*)d_out);
}